// Round 10
// baseline (1761.788 us; speedup 1.0000x reference)
//
#include <hip/hip_runtime.h>

#define BB 100000
#define NN 20
#define ND 128
#define TD 64
#define CD 192
#define HD 128
#define NH 4
#define DH 32
#define NL 2
#define WLS 311296  // per-layer WF stride (u16): 608 tiles x 512

typedef __attribute__((ext_vector_type(8))) short bf16x8;
typedef __attribute__((ext_vector_type(4))) float f32x4;

static __device__ __forceinline__ float bf2f(unsigned short u) {
  return __uint_as_float(((unsigned)u) << 16);
}
static __device__ __forceinline__ unsigned short f2bf(float x) {
  unsigned b = __float_as_uint(x);
  return (unsigned short)((b + 0x7FFFu + ((b >> 16) & 1u)) >> 16);
}
static __device__ __forceinline__ bf16x8 load_a8(const float* p) {
  float4 a = *(const float4*)p, b = *(const float4*)(p + 4);
  bf16x8 r;
  r[0] = (short)f2bf(a.x); r[1] = (short)f2bf(a.y);
  r[2] = (short)f2bf(a.z); r[3] = (short)f2bf(a.w);
  r[4] = (short)f2bf(b.x); r[5] = (short)f2bf(b.y);
  r[6] = (short)f2bf(b.z); r[7] = (short)f2bf(b.w);
  return r;
}
// Pack (within-tile k=wk, col=c16) -> fragment element index (m89 layout).
static __device__ __forceinline__ int fragidx(int wk, int c16) {
  return (((wk >> 3) << 4) | c16) * 8 + (wk & 7);
}

// ---------------------------------------------------------------------------
// R10: R9's weight folds kept (M = Wq Wk^T, WC = Wv Wo), but GEMMs row-tiled:
// 64 rows/block, 8 waves, B-frags in REGISTERS across 4 row-tiles per k-tile.
// Fixes R9's regression (16-row blocks re-read the 3x-larger folded B from L2:
// 1.84 GB/layer; now 460 MB). Per-layer WF tile map: M 0-287 (kt*48+nt),
// WC 288-479 (kt*8+nt), W1 480-543 (kt*16+nt), W2 544-607 (kt*8+nt).
// ---------------------------------------------------------------------------

__global__ __launch_bounds__(192) void precomp_M(
    const float* __restrict__ Wq, const float* __restrict__ Wk,
    unsigned short* __restrict__ WF) {
  int e = blockIdx.x;               // (l*4+h)*192 + c1
  int c1 = e % CD;
  int h = (e / CD) % NH;
  int l = e / (CD * NH);
  int c2 = threadIdx.x;
  const float* wq = Wq + ((size_t)l * CD + c1) * HD + h * DH;
  const float* wk = Wk + ((size_t)l * CD + c2) * HD + h * DH;
  float acc = 0.f;
#pragma unroll
  for (int d = 0; d < DH; ++d) acc += wq[d] * wk[d];
  int n = h * CD + c2;
  int nt = n >> 4, c16 = n & 15;
  int kt = c1 >> 5, wk2 = c1 & 31;
  WF[(size_t)l * WLS + (size_t)(kt * 48 + nt) * 512 + fragidx(wk2, c16)] =
      f2bf(acc);
}

__global__ __launch_bounds__(192) void precomp_pk(
    const float* __restrict__ bq, const float* __restrict__ Wk,
    float* __restrict__ pk) {
  int e = blockIdx.x;  // l*4+h
  int h = e % NH, l = e / NH;
  int c2 = threadIdx.x;
  const float* bqp = bq + (size_t)l * HD + h * DH;
  const float* wk = Wk + ((size_t)l * CD + c2) * HD + h * DH;
  float acc = 0.f;
#pragma unroll
  for (int d = 0; d < DH; ++d) acc += bqp[d] * wk[d];
  pk[(size_t)l * 768 + h * CD + c2] = acc;
}

__global__ __launch_bounds__(128) void precomp_WC(
    const float* __restrict__ Wv, const float* __restrict__ Wo,
    unsigned short* __restrict__ WF) {
  int e = blockIdx.x;  // l*768 + k
  int k = e % 768, l = e / 768;
  int c = k % CD, h = k / CD;
  int j = threadIdx.x;
  const float* wv = Wv + ((size_t)l * CD + c) * HD + h * DH;
  const float* wo = Wo + ((size_t)l * HD + h * DH) * ND + j;
  float acc = 0.f;
#pragma unroll
  for (int d = 0; d < DH; ++d) acc += wv[d] * wo[(size_t)d * ND];
  int kt = k >> 5, wk2 = k & 31;
  int nt = j >> 4, c16 = j & 15;
  WF[(size_t)l * WLS + 147456 + (size_t)(kt * 8 + nt) * 512 +
     fragidx(wk2, c16)] = f2bf(acc);
}

__global__ __launch_bounds__(128) void precomp_bC(
    const float* __restrict__ bv, const float* __restrict__ bo,
    const float* __restrict__ Wo, float* __restrict__ bC) {
  int l = blockIdx.x;
  int j = threadIdx.x;
  float acc = bo[(size_t)l * ND + j];
  for (int k = 0; k < HD; ++k)
    acc += bv[(size_t)l * HD + k] * Wo[((size_t)l * HD + k) * ND + j];
  bC[(size_t)l * ND + j] = acc;
}

__global__ __launch_bounds__(256) void conv_w2(
    const float* __restrict__ W1, const float* __restrict__ W2,
    unsigned short* __restrict__ WF) {
  int t = blockIdx.x;            // 0..255
  int l = t >> 7, tt = t & 127;
#pragma unroll
  for (int e = 0; e < 2; ++e) {
    int idx = threadIdx.x * 2 + e;
    int lane = idx >> 3, j = idx & 7;
    int wk = ((lane >> 4) << 3) + j;
    int c16 = lane & 15;
    float v;
    size_t dst;
    if (tt < 64) {               // W1 [128x256]
      int kt = tt >> 4, n2 = tt & 15;
      v = W1[((size_t)l * ND + kt * 32 + wk) * (2 * ND) + n2 * 16 + c16];
      dst = (size_t)l * WLS + 245760 + (size_t)tt * 512 + idx;
    } else {                     // W2 [256x128]
      int t2 = tt - 64;
      int kt = t2 >> 3, n2 = t2 & 7;
      v = W2[((size_t)l * 2 * ND + kt * 32 + wk) * ND + n2 * 16 + c16];
      dst = (size_t)l * WLS + 278528 + (size_t)t2 * 512 + idx;
    }
    WF[dst] = f2bf(v);
  }
}

__global__ __launch_bounds__(256) void prep_tq(
    const float* __restrict__ ntime, const float* __restrict__ tf,
    const float* __restrict__ tp, float* __restrict__ tqf) {
  int i = blockIdx.x * 256 + threadIdx.x;
  int b = i >> 6, j = i & 63;
  tqf[i] = __cosf(ntime[b] * tf[j] + tp[j]);
}

__global__ __launch_bounds__(256) void prep_mb(const int* __restrict__ mask,
                                               unsigned* __restrict__ mb) {
  int e = blockIdx.x * 256 + threadIdx.x;
  if (e < BB) {
    unsigned m = 0;
    for (int n = 0; n < NN; ++n)
      m |= (mask[(size_t)e * NN + n] != 0 ? 1u : 0u) << n;
    mb[e] = m;
  }
}

// r = [x|tq] @ M + pk. Row-tiled: 64 rows/block, 8 waves x TN=6 ntiles,
// B-frags in registers per kt shared across 4 row-tiles. bf16 out.
__global__ __launch_bounds__(512) void gemm_rt(
    const float* __restrict__ A, const float* __restrict__ A2,
    const unsigned short* __restrict__ BF, const float* __restrict__ pk,
    unsigned short* __restrict__ C) {
  const int tid = threadIdx.x;
  const int wv = tid >> 6, lane = tid & 63;
  const int m0 = blockIdx.x << 6;
  const int kgrp = (lane >> 4) << 3;
  f32x4 acc[4][6];
#pragma unroll
  for (int rt = 0; rt < 4; ++rt)
#pragma unroll
    for (int i = 0; i < 6; ++i) acc[rt][i] = f32x4{0.f, 0.f, 0.f, 0.f};
#pragma unroll
  for (int kt = 0; kt < 6; ++kt) {
    bf16x8 bfr[6];
#pragma unroll
    for (int i = 0; i < 6; ++i)
      bfr[i] = *(const bf16x8*)(BF + (((size_t)(kt * 48 + wv * 6 + i)) << 9) +
                                (lane << 3));
#pragma unroll
    for (int rt = 0; rt < 4; ++rt) {
      int ar = m0 + rt * 16 + (lane & 15);
      if (ar > BB - 1) ar = BB - 1;
      bf16x8 af;
      if (kt < 4)
        af = load_a8(A + (size_t)ar * ND + kt * 32 + kgrp);
      else
        af = load_a8(A2 + (size_t)ar * TD + (kt - 4) * 32 + kgrp);
#pragma unroll
      for (int i = 0; i < 6; ++i)
        acc[rt][i] = __builtin_amdgcn_mfma_f32_16x16x32_bf16(af, bfr[i],
                                                             acc[rt][i], 0, 0, 0);
    }
  }
#pragma unroll
  for (int rt = 0; rt < 4; ++rt) {
    int crow = m0 + rt * 16 + ((lane >> 4) << 2);
#pragma unroll
    for (int i = 0; i < 6; ++i) {
      int col = (wv * 6 + i) * 16 + (lane & 15);
      float bv = pk[col];
#pragma unroll
      for (int rr = 0; rr < 4; ++rr) {
        if (crow + rr < BB)
          C[(size_t)(crow + rr) * 768 + col] = f2bf(acc[rt][i][rr] + bv);
      }
    }
  }
}

// Generic 16-row-block GEMM (kept for FF1: small B, amortization fine).
template <int TN, int ABF, int OBF>
__global__ __launch_bounds__(256) void gemm16(
    const void* __restrict__ A, int lda,
    const unsigned short* __restrict__ BF,
    int ktiles, int ntiles,
    const float* __restrict__ bias,
    void* __restrict__ C, int ldc, int relu) {
  const int tid = threadIdx.x;
  const int wv = tid >> 6, lane = tid & 63;
  const int NW = blockDim.x >> 6;
  const int m0 = blockIdx.x << 4;
  const int arow = m0 + (lane & 15);
  const int kgrp = (lane >> 4) << 3;
  f32x4 acc[TN];
#pragma unroll
  for (int i = 0; i < TN; ++i) acc[i] = f32x4{0.f, 0.f, 0.f, 0.f};
  for (int kt = 0; kt < ktiles; ++kt) {
    bf16x8 af;
    if (ABF)
      af = *(const bf16x8*)((const unsigned short*)A + (size_t)arow * lda +
                            kt * 32 + kgrp);
    else
      af = load_a8((const float*)A + (size_t)arow * lda + kt * 32 + kgrp);
#pragma unroll
    for (int i = 0; i < TN; ++i) {
      int nt = wv + NW * i;
      bf16x8 bf = *(const bf16x8*)(BF + (((size_t)(kt * ntiles + nt)) << 9) +
                                   (lane << 3));
      acc[i] = __builtin_amdgcn_mfma_f32_16x16x32_bf16(af, bf, acc[i], 0, 0, 0);
    }
  }
  const int crow = m0 + ((lane >> 4) << 2);
#pragma unroll
  for (int i = 0; i < TN; ++i) {
    int nt = wv + NW * i;
    int col = nt * 16 + (lane & 15);
    float bv = bias ? bias[col] : 0.f;
#pragma unroll
    for (int rr = 0; rr < 4; ++rr) {
      float v = acc[i][rr] + bv;
      if (relu) v = fmaxf(v, 0.f);
      if (OBF)
        ((unsigned short*)C)[(size_t)(crow + rr) * ldc + col] = f2bf(v);
      else
        ((float*)C)[(size_t)(crow + rr) * ldc + col] = v;
    }
  }
}

// Row-tiled GEMM (N=128, bf16 A) + bias + residual + LayerNorm -> xout f32.
// 64 rows/block, 8 waves (TN=1 each), 4 row-tiles, B-frag in reg per kt.
// CLS=1: classifier (relu(x@Wc1+bc1)@Wc2+bc2 -> sigmoid) from LDS instead.
template <int KT, int CLS>
__global__ __launch_bounds__(512) void gemm_ln_rt(
    const unsigned short* __restrict__ A, int lda,
    const unsigned short* __restrict__ BF,
    const float* __restrict__ bias, const float* __restrict__ res,
    const float* __restrict__ gamma, const float* __restrict__ beta,
    float* __restrict__ xout,
    const float* __restrict__ Wc1, const float* __restrict__ bc1,
    const float* __restrict__ Wc2, const float* __restrict__ bc2,
    float* __restrict__ out) {
  __shared__ float Cs[64][132];
  __shared__ float hsh[CLS ? 64 : 1][64];
  const int tid = threadIdx.x;
  const int wv = tid >> 6, lane = tid & 63;
  const int m0 = blockIdx.x << 6;
  const int kgrp = (lane >> 4) << 3;
  f32x4 acc[4];
#pragma unroll
  for (int rt = 0; rt < 4; ++rt) acc[rt] = f32x4{0.f, 0.f, 0.f, 0.f};
#pragma unroll
  for (int kt = 0; kt < KT; ++kt) {
    bf16x8 bf = *(const bf16x8*)(BF + (((size_t)(kt * 8 + wv)) << 9) +
                                 (lane << 3));
#pragma unroll
    for (int rt = 0; rt < 4; ++rt) {
      int ar = m0 + rt * 16 + (lane & 15);
      if (ar > BB - 1) ar = BB - 1;
      bf16x8 af = *(const bf16x8*)(A + (size_t)ar * lda + kt * 32 + kgrp);
      acc[rt] = __builtin_amdgcn_mfma_f32_16x16x32_bf16(af, bf, acc[rt], 0, 0, 0);
    }
  }
  {
    int c0 = wv * 16 + (lane & 15);
    float bv = bias[c0];
#pragma unroll
    for (int rt = 0; rt < 4; ++rt) {
      int lrow = rt * 16 + ((lane >> 4) << 2);
#pragma unroll
      for (int rr = 0; rr < 4; ++rr) Cs[lrow + rr][c0] = acc[rt][rr] + bv;
    }
  }
  __syncthreads();
#pragma unroll
  for (int k = 0; k < 8; ++k) {
    int rw = wv * 8 + k;
    if (m0 + rw < BB) {
      size_t grow = (size_t)(m0 + rw) * ND;
      float y0 = Cs[rw][lane] + res[grow + lane];
      float y1 = Cs[rw][lane + 64] + res[grow + lane + 64];
      float s = y0 + y1, ss = y0 * y0 + y1 * y1;
#pragma unroll
      for (int off = 32; off > 0; off >>= 1) {
        s += __shfl_xor(s, off);
        ss += __shfl_xor(ss, off);
      }
      float mean = s * (1.f / ND);
      float var = ss * (1.f / ND) - mean * mean;
      float rstd = rsqrtf(var + 1e-5f);
      float x0 = (y0 - mean) * rstd * gamma[lane] + beta[lane];
      float x1 = (y1 - mean) * rstd * gamma[lane + 64] + beta[lane + 64];
      if (CLS) {
        Cs[rw][lane] = x0;
        Cs[rw][lane + 64] = x1;
      } else {
        xout[grow + lane] = x0;
        xout[grow + lane + 64] = x1;
      }
    }
  }
  if (CLS) {
    __syncthreads();
#pragma unroll
    for (int rep = 0; rep < 8; ++rep) {
      int idx = rep * 512 + tid;
      int row = idx >> 6, j = idx & 63;
      float a = 0.f;
      for (int c = 0; c < ND; ++c) a += Cs[row][c] * Wc1[c * 64 + j];
      hsh[row][j] = fmaxf(a + bc1[j], 0.f);
    }
    __syncthreads();
#pragma unroll
    for (int k = 0; k < 8; ++k) {
      int row = wv * 8 + k;
      float p = hsh[row][lane] * Wc2[lane];
#pragma unroll
      for (int off = 32; off > 0; off >>= 1) p += __shfl_xor(p, off);
      if (lane == 0 && m0 + row < BB)
        out[m0 + row] = 1.f / (1.f + expf(-(p + bc2[0])));
    }
  }
}

// Attention, 2 elements/block, kc computed in-kernel (nbf + cos time enc).
// r,u bf16; u aliases r (element-private; r staged to LDS first).
__global__ __launch_bounds__(256) void attn_b(
    const float* __restrict__ nbf, const float* __restrict__ nbt,
    const float* __restrict__ tf, const float* __restrict__ tp,
    const unsigned* __restrict__ mb, const unsigned short* __restrict__ r,
    unsigned short* __restrict__ u) {
  __shared__ __align__(16) unsigned short kcb[2][NN][200];
  __shared__ __align__(16) float rs[2][768];
  __shared__ __align__(16) float scs[2][NH][NN];
  __shared__ unsigned msks[2];
  const int tid = threadIdx.x;
  const size_t e0 = (size_t)blockIdx.x * 2;

  if (tid < 192) {
    uint4 v = *(const uint4*)(r + e0 * 768 + tid * 8);
    const unsigned short* pv = (const unsigned short*)&v;
    float* dst = &rs[0][0] + tid * 8;
#pragma unroll
    for (int k = 0; k < 8; ++k) dst[k] = bf2f(pv[k]);
  }
  for (int i = tid; i < 2 * NN * 32; i += 256) {
    int el = i / (NN * 32), rem = i % (NN * 32);
    int n = rem >> 5, cq = rem & 31;
    float4 v = *(const float4*)&nbf[((e0 + el) * NN + n) * ND + cq * 4];
    ushort4 o;
    o.x = f2bf(v.x); o.y = f2bf(v.y); o.z = f2bf(v.z); o.w = f2bf(v.w);
    *(ushort4*)&kcb[el][n][cq * 4] = o;
  }
  for (int i = tid; i < 2 * NN * 32; i += 256) {
    int el = i / (NN * 32), rem = i % (NN * 32);
    int n = rem >> 5, jp = (rem & 31) * 2;
    float t = nbt[(e0 + el) * NN + n];
    unsigned a = f2bf(__cosf(t * tf[jp] + tp[jp]));
    unsigned b = f2bf(__cosf(t * tf[jp + 1] + tp[jp + 1]));
    *(unsigned*)&kcb[el][n][ND + jp] = a | (b << 16);
  }
  if (tid < 2) msks[tid] = mb[e0 + tid];
  __syncthreads();
  if (tid < 2 * NH * NN) {
    int el = tid / (NH * NN), rem = tid % (NH * NN);
    int h = rem / NN, n = rem % NN;
    const float* rp = &rs[el][h * CD];
    const unsigned short* kp = &kcb[el][n][0];
    float acc = 0.f;
    for (int c = 0; c < CD; c += 4) {
      float4 rv = *(const float4*)&rp[c];
      ushort4 kv = *(const ushort4*)&kp[c];
      acc += rv.x * bf2f(kv.x) + rv.y * bf2f(kv.y) + rv.z * bf2f(kv.z) +
             rv.w * bf2f(kv.w);
    }
    scs[el][h][n] =
        ((msks[el] >> n) & 1u) ? acc * 0.17677669529663687f : -1e9f;
  }
  __syncthreads();
  if (tid < 2 * NH) {
    int el = tid >> 2, h = tid & 3;
    float mx = -3.4e38f;
#pragma unroll
    for (int n = 0; n < NN; ++n) mx = fmaxf(mx, scs[el][h][n]);
    float ev[NN], s = 0.f;
#pragma unroll
    for (int n = 0; n < NN; ++n) { ev[n] = __expf(scs[el][h][n] - mx); s += ev[n]; }
    float inv = 1.f / s;
#pragma unroll
    for (int n = 0; n < NN; ++n) scs[el][h][n] = ev[n] * inv;
  }
  __syncthreads();
  for (int i = tid; i < 2 * NH * (CD / 4); i += 256) {
    int el = i / (NH * 48), rem = i % (NH * 48);
    int h = rem / 48, cq = (rem % 48) * 4;
    float a0 = 0.f, a1 = 0.f, a2 = 0.f, a3 = 0.f;
#pragma unroll
    for (int n = 0; n < NN; ++n) {
      float w = scs[el][h][n];
      ushort4 kv = *(const ushort4*)&kcb[el][n][cq];
      a0 += w * bf2f(kv.x); a1 += w * bf2f(kv.y);
      a2 += w * bf2f(kv.z); a3 += w * bf2f(kv.w);
    }
    ushort4 o;
    o.x = f2bf(a0); o.y = f2bf(a1); o.z = f2bf(a2); o.w = f2bf(a3);
    *(ushort4*)&u[(e0 + el) * 768 + h * CD + cq] = o;
  }
}

// ---------------------------------------------------------------------------
// Tier C fallback (R5 fused kernel) if workspace is tiny.
// ---------------------------------------------------------------------------
#define G 2
#define T 256
#define KCS 196
#define RUS 772

__global__ __launch_bounds__(T, 4) void tgat_fused(
    const float* __restrict__ nf, const float* __restrict__ nbf,
    const float* __restrict__ nt, const float* __restrict__ nbt,
    const float* __restrict__ tf, const float* __restrict__ tp,
    const float* __restrict__ Wq, const float* __restrict__ bq,
    const float* __restrict__ Wk,
    const float* __restrict__ Wv, const float* __restrict__ bv,
    const float* __restrict__ Wo, const float* __restrict__ bo,
    const float* __restrict__ W1, const float* __restrict__ b1,
    const float* __restrict__ W2, const float* __restrict__ b2,
    const float* __restrict__ g1, const float* __restrict__ be1,
    const float* __restrict__ g2, const float* __restrict__ be2,
    const float* __restrict__ Wc1, const float* __restrict__ bc1,
    const float* __restrict__ Wc2, const float* __restrict__ bc2,
    const int* __restrict__ mask,
    float* __restrict__ out) {
  __shared__ __align__(16) unsigned short kc[G][NN][KCS];
  __shared__ __align__(16) float xs[G][ND];
  __shared__ __align__(16) float tqs[G][TD];
  __shared__ __align__(16) float ys[G][HD];
  __shared__ __align__(16) float rus[G][RUS];
  __shared__ __align__(16) float scs[G][NH][NN];
  __shared__ __align__(16) float h1s[G][2 * ND];
  __shared__ __align__(16) unsigned msks[G];
  float* asv = &h1s[0][0];
  const int tid = threadIdx.x;
  const int b0 = blockIdx.x * G;
  {
    int g = tid >> 7, j = tid & 127;
    xs[g][j] = nf[(b0 + g) * ND + j];
  }
  if (tid < G * TD) {
    int g = tid >> 6, j = tid & 63;
    tqs[g][j] = __cosf(nt[b0 + g] * tf[j] + tp[j]);
  }
  if (tid < G) {
    unsigned m = 0;
    for (int n = 0; n < NN; ++n)
      m |= (mask[(b0 + tid) * NN + n] != 0 ? 1u : 0u) << n;
    msks[tid] = m;
  }
  for (int idx = tid; idx < G * NN * (ND / 4); idx += T) {
    int g = idx / (NN * 32), rem = idx % (NN * 32);
    int n = rem >> 5, cq = rem & 31;
    float4 v = *(const float4*)&nbf[(((b0 + g) * NN + n) * ND) + cq * 4];
    ushort4 o;
    o.x = f2bf(v.x); o.y = f2bf(v.y); o.z = f2bf(v.z); o.w = f2bf(v.w);
    *(ushort4*)&kc[g][n][cq * 4] = o;
  }
  for (int idx = tid; idx < G * NN * TD; idx += T) {
    int g = idx / (NN * TD), rem = idx % (NN * TD);
    int n = rem >> 6, j = rem & 63;
    kc[g][n][ND + j] = f2bf(__cosf(nbt[(b0 + g) * NN + n] * tf[j] + tp[j]));
  }
  __syncthreads();
  const float scale = 0.17677669529663687f;
  for (int l = 0; l < NL; ++l) {
    {
      int g = tid >> 7, j = tid & 127;
      const float* wq = Wq + (l * CD) * HD + j;
      float acc = bq[l * HD + j];
      for (int c = 0; c < CD; c += 4) {
        float4 qv = (c < ND) ? *(const float4*)&xs[g][c]
                             : *(const float4*)&tqs[g][c - ND];
        acc += qv.x * wq[(c + 0) * HD] + qv.y * wq[(c + 1) * HD] +
               qv.z * wq[(c + 2) * HD] + qv.w * wq[(c + 3) * HD];
      }
      ys[g][j] = acc;
    }
    __syncthreads();
    for (int rep = 0; rep < 3; ++rep) {
      int i = rep * T + tid;
      int h = i / CD;
      int c2 = i - h * CD;
      const float* wk = Wk + (l * CD + c2) * HD + h * DH;
      const float* yp0 = &ys[0][h * DH];
      const float* yp1 = &ys[1][h * DH];
      float a0 = 0.f, a1 = 0.f;
#pragma unroll
      for (int d = 0; d < DH; d += 4) {
        float4 w4 = *(const float4*)&wk[d];
        float4 y0 = *(const float4*)&yp0[d];
        float4 y1 = *(const float4*)&yp1[d];
        a0 += y0.x * w4.x + y0.y * w4.y + y0.z * w4.z + y0.w * w4.w;
        a1 += y1.x * w4.x + y1.y * w4.y + y1.z * w4.z + y1.w * w4.w;
      }
      rus[0][i] = a0;
      rus[1][i] = a1;
    }
    __syncthreads();
    if (tid < G * NH * NN) {
      int g = tid / (NH * NN), rem = tid % (NH * NN);
      int h = rem / NN, n = rem % NN;
      const float* rp = &rus[g][h * CD];
      const unsigned short* kp = &kc[g][n][0];
      float acc = 0.f;
      for (int c = 0; c < CD; c += 4) {
        float4 rv = *(const float4*)&rp[c];
        ushort4 kv = *(const ushort4*)&kp[c];
        acc += rv.x * bf2f(kv.x) + rv.y * bf2f(kv.y) + rv.z * bf2f(kv.z) +
               rv.w * bf2f(kv.w);
      }
      scs[g][h][n] = ((msks[g] >> n) & 1u) ? acc * scale : -1e9f;
    }
    __syncthreads();
    if (tid < G * NH) {
      int g = tid / NH, h = tid % NH;
      float mx = -3.4e38f;
#pragma unroll
      for (int n = 0; n < NN; ++n) mx = fmaxf(mx, scs[g][h][n]);
      float ev[NN], s = 0.f;
#pragma unroll
      for (int n = 0; n < NN; ++n) { ev[n] = __expf(scs[g][h][n] - mx); s += ev[n]; }
      float inv = 1.f / s;
#pragma unroll
      for (int n = 0; n < NN; ++n) scs[g][h][n] = ev[n] * inv;
    }
    __syncthreads();
    for (int flat = tid; flat < G * NH * (CD / 4); flat += T) {
      int g = flat / (NH * 48), iq = flat % (NH * 48);
      int h = iq / 48, c = (iq % 48) * 4;
      const unsigned short* kp = &kc[g][0][0];
      float a0 = 0.f, a1 = 0.f, a2 = 0.f, a3 = 0.f;
#pragma unroll
      for (int n = 0; n < NN; ++n) {
        float w = scs[g][h][n];
        ushort4 kv = *(const ushort4*)&kp[n * KCS + c];
        a0 += w * bf2f(kv.x); a1 += w * bf2f(kv.y);
        a2 += w * bf2f(kv.z); a3 += w * bf2f(kv.w);
      }
      *(float4*)&rus[g][h * CD + c] = make_float4(a0, a1, a2, a3);
    }
    __syncthreads();
    {
      int j = tid & (HD - 1);
      int g = tid >> 7;
      int h = j >> 5;
      const float* wv = Wv + (l * CD) * HD + j;
      float acc = 0.f;
      for (int c = 0; c < CD; c += 4) {
        float4 uv = *(const float4*)&rus[g][h * CD + c];
        acc += uv.x * wv[(c + 0) * HD] + uv.y * wv[(c + 1) * HD] +
               uv.z * wv[(c + 2) * HD] + uv.w * wv[(c + 3) * HD];
      }
      asv[g * HD + j] = acc + bv[l * HD + j];
    }
    __syncthreads();
    {
      int j = tid & (ND - 1);
      int g = tid >> 7;
      const float* wo = Wo + (l * HD) * ND + j;
      float acc = 0.f;
      for (int c = 0; c < HD; c += 4) {
        float4 av = *(const float4*)&asv[g * HD + c];
        acc += av.x * wo[(c + 0) * ND] + av.y * wo[(c + 1) * ND] +
               av.z * wo[(c + 2) * ND] + av.w * wo[(c + 3) * ND];
      }
      rus[g][j] = acc + bo[l * ND + j];
    }
    __syncthreads();
    if (tid < G * 64) {
      int g = tid >> 6, lane = tid & 63;
      float y0 = xs[g][lane] + rus[g][lane];
      float y1 = xs[g][lane + 64] + rus[g][lane + 64];
      float s = y0 + y1, ss = y0 * y0 + y1 * y1;
#pragma unroll
      for (int off = 32; off > 0; off >>= 1) {
        s += __shfl_xor(s, off);
        ss += __shfl_xor(ss, off);
      }
      float mean = s * (1.f / ND);
      float var = ss * (1.f / ND) - mean * mean;
      float rstd = rsqrtf(var + 1e-5f);
      xs[g][lane] = (y0 - mean) * rstd * g1[l * ND + lane] + be1[l * ND + lane];
      xs[g][lane + 64] =
          (y1 - mean) * rstd * g1[l * ND + lane + 64] + be1[l * ND + lane + 64];
    }
    __syncthreads();
    {
      int j = tid;
      const float* w1p = W1 + (l * ND) * (2 * ND) + j;
      float acc0 = 0.f, acc1 = 0.f;
      for (int c = 0; c < ND; c += 4) {
        float w0 = w1p[(c + 0) * 2 * ND], wa = w1p[(c + 1) * 2 * ND],
              w2 = w1p[(c + 2) * 2 * ND], w3 = w1p[(c + 3) * 2 * ND];
        float4 x0 = *(const float4*)&xs[0][c];
        float4 x1 = *(const float4*)&xs[1][c];
        acc0 += x0.x * w0 + x0.y * wa + x0.z * w2 + x0.w * w3;
        acc1 += x1.x * w0 + x1.y * wa + x1.z * w2 + x1.w * w3;
      }
      float b1v = b1[l * 2 * ND + j];
      h1s[0][j] = fmaxf(acc0 + b1v, 0.f);
      h1s[1][j] = fmaxf(acc1 + b1v, 0.f);
    }
    __syncthreads();
    {
      int j = tid & (ND - 1);
      int g = tid >> 7;
      const float* w2p = W2 + (l * 2 * ND) * ND + j;
      float acc = 0.f;
      for (int c = 0; c < 2 * ND; c += 4) {
        float4 hv = *(const float4*)&h1s[g][c];
        acc += hv.x * w2p[(c + 0) * ND] + hv.y * w2p[(c + 1) * ND] +
               hv.z * w2p[(c + 2) * ND] + hv.w * w2p[(c + 3) * ND];
      }
      rus[g][j] = acc + b2[l * ND + j];
    }
    __syncthreads();
    if (tid < G * 64) {
      int g = tid >> 6, lane = tid & 63;
      float y0 = xs[g][lane] + rus[g][lane];
      float y1 = xs[g][lane + 64] + rus[g][lane + 64];
      float s = y0 + y1, ss = y0 * y0 + y1 * y1;
#pragma unroll
      for (int off = 32; off > 0; off >>= 1) {
        s += __shfl_xor(s, off);
        ss += __shfl_xor(ss, off);
      }
      float mean = s * (1.f / ND);
      float var = ss * (1.f / ND) - mean * mean;
      float rstd = rsqrtf(var + 1e-5f);
      xs[g][lane] = (y0 - mean) * rstd * g2[l * ND + lane] + be2[l * ND + lane];
      xs[g][lane + 64] =
          (y1 - mean) * rstd * g2[l * ND + lane + 64] + be2[l * ND + lane + 64];
    }
    __syncthreads();
  }
  if (tid < G * 64) {
    int j = tid & 63;
    int g = tid >> 6;
    const float* wc = Wc1 + j;
    float acc = 0.f;
    for (int c = 0; c < ND; c += 4) {
      float4 xv = *(const float4*)&xs[g][c];
      acc += xv.x * wc[(c + 0) * 64] + xv.y * wc[(c + 1) * 64] +
             xv.z * wc[(c + 2) * 64] + xv.w * wc[(c + 3) * 64];
    }
    ((float*)scs)[g * 64 + j] = fmaxf(acc + bc1[j], 0.f);
  }
  __syncthreads();
  if (tid < G * 64) {
    int g = tid >> 6, lane = tid & 63;
    float p = ((float*)scs)[g * 64 + lane] * Wc2[lane];
#pragma unroll
    for (int off = 32; off > 0; off >>= 1) p += __shfl_xor(p, off);
    if (lane == 0) {
      float z = p + bc2[0];
      out[b0 + g] = 1.f / (1.f + expf(-z));
    }
  }
}

extern "C" void kernel_launch(void* const* d_in, const int* in_sizes, int n_in,
                              void* d_out, int out_size, void* d_ws,
                              size_t ws_size, hipStream_t stream) {
  (void)in_sizes; (void)n_in; (void)out_size;
  const float* nf  = (const float*)d_in[0];
  const float* nbf = (const float*)d_in[1];
  const float* ntm = (const float*)d_in[2];
  const float* nbt = (const float*)d_in[3];
  const float* tf  = (const float*)d_in[4];
  const float* tp  = (const float*)d_in[5];
  const float* Wq  = (const float*)d_in[6];
  const float* bq  = (const float*)d_in[7];
  const float* Wk  = (const float*)d_in[8];
  // d_in[9] = bk: n-uniform score shift -> softmax-invariant -> dropped
  const float* Wv  = (const float*)d_in[10];
  const float* bv  = (const float*)d_in[11];
  const float* Wo  = (const float*)d_in[12];
  const float* bo  = (const float*)d_in[13];
  const float* W1  = (const float*)d_in[14];
  const float* b1  = (const float*)d_in[15];
  const float* W2  = (const float*)d_in[16];
  const float* b2  = (const float*)d_in[17];
  const float* g1  = (const float*)d_in[18];
  const float* be1 = (const float*)d_in[19];
  const float* g2  = (const float*)d_in[20];
  const float* be2 = (const float*)d_in[21];
  const float* Wc1 = (const float*)d_in[22];
  const float* bc1 = (const float*)d_in[23];
  const float* Wc2 = (const float*)d_in[24];
  const float* bc2 = (const float*)d_in[25];
  const int* mask  = (const int*)d_in[26];
  float* out = (float*)d_out;

  // Workspace (bytes) — identical layout to R9:
  //   WF 0..1,245,184 | pk +6,144 | bC +1,024 | mb +400,000 | tqf +25.6M
  //   rb(bf16,u-alias) +153.6M | h1b(bf16) +51.2M | xfb(f32) +51.2M
  const size_t NEED = 283252352ull;
  if (ws_size >= NEED) {
    char* w = (char*)d_ws;
    unsigned short* WF = (unsigned short*)w;
    float* pk = (float*)(w + 1245184);
    float* bC = (float*)(w + 1251328);
    unsigned* mb = (unsigned*)(w + 1252352);
    float* tqf = (float*)(w + 1652352);
    unsigned short* rb = (unsigned short*)(w + 27252352);
    unsigned short* h1b = (unsigned short*)(w + 180852352);
    float* xfb = (float*)(w + 232052352);

    precomp_M<<<NL * NH * CD, CD, 0, stream>>>(Wq, Wk, WF);
    precomp_pk<<<NL * NH, CD, 0, stream>>>(bq, Wk, pk);
    precomp_WC<<<NL * 768, ND, 0, stream>>>(Wv, Wo, WF);
    precomp_bC<<<NL, ND, 0, stream>>>(bv, bo, Wo, bC);
    conv_w2<<<256, 256, 0, stream>>>(W1, W2, WF);
    prep_tq<<<25000, 256, 0, stream>>>(ntm, tf, tp, tqf);
    prep_mb<<<(BB + 255) / 256, 256, 0, stream>>>(mask, mb);

    const int GRT = (BB + 63) / 64;  // 1563 row-tiled blocks
    const float* xsrc = nf;
    for (int l = 0; l < NL; ++l) {
      const unsigned short* WFl = WF + (size_t)l * WLS;
      // r = [x|tq] @ M + pk  (row-tiled, bf16 out)
      gemm_rt<<<GRT, 512, 0, stream>>>(xsrc, tqf, WFl, pk + l * 768, rb);
      // scores/softmax/u (u bf16 overwrites r, element-private)
      attn_b<<<50000, 256, 0, stream>>>(nbf, nbt, tf, tp, mb, rb, rb);
      // x = LN1(x + u @ WC + bC)  (K=768, row-tiled)
      gemm_ln_rt<24, 0><<<GRT, 512, 0, stream>>>(
          rb, 768, WFl + 147456, bC + l * ND, xsrc, g1 + l * ND,
          be1 + l * ND, xfb, nullptr, nullptr, nullptr, nullptr, nullptr);
      // h1 = relu(x @ W1 + b1)  (bf16 out; small B, 16-row blocks fine)
      gemm16<4, 0, 1><<<6250, 256, 0, stream>>>(
          xfb, ND, WFl + 245760, 4, 16, b1 + l * 2 * ND, h1b, 2 * ND, 1);
      // x = LN2(x + h1 @ W2 + b2); final layer: fused classifier
      if (l == NL - 1)
        gemm_ln_rt<8, 1><<<GRT, 512, 0, stream>>>(
            h1b, 2 * ND, WFl + 278528, b2 + l * ND, xfb, g2 + l * ND,
            be2 + l * ND, xfb, Wc1, bc1, Wc2, bc2, out);
      else
        gemm_ln_rt<8, 0><<<GRT, 512, 0, stream>>>(
            h1b, 2 * ND, WFl + 278528, b2 + l * ND, xfb, g2 + l * ND,
            be2 + l * ND, xfb, nullptr, nullptr, nullptr, nullptr, nullptr);
      xsrc = xfb;
    }
  } else {
    tgat_fused<<<BB / G, T, 0, stream>>>(nf, nbf, ntm, nbt, tf, tp, Wq, bq, Wk,
                                         Wv, bv, Wo, bo, W1, b1, W2, b2, g1,
                                         be1, g2, be2, Wc1, bc1, Wc2, bc2,
                                         mask, out);
  }
}

// Round 11
// 1404.588 us; speedup vs baseline: 1.2543x; 1.2543x over previous
//
#include <hip/hip_runtime.h>

#define BB 100000
#define NN 20
#define ND 128
#define TD 64
#define CD 192
#define HD 128
#define NH 4
#define DH 32
#define NL 2

typedef __attribute__((ext_vector_type(8))) short bf16x8;
typedef __attribute__((ext_vector_type(4))) float f32x4;

static __device__ __forceinline__ float bf2f(unsigned short u) {
  return __uint_as_float(((unsigned)u) << 16);
}
static __device__ __forceinline__ unsigned short f2bf(float x) {
  unsigned b = __float_as_uint(x);
  return (unsigned short)((b + 0x7FFFu + ((b >> 16) & 1u)) >> 16);
}
static __device__ __forceinline__ bf16x8 load_a8(const float* p) {
  float4 a = *(const float4*)p, b = *(const float4*)(p + 4);
  bf16x8 r;
  r[0] = (short)f2bf(a.x); r[1] = (short)f2bf(a.y);
  r[2] = (short)f2bf(a.z); r[3] = (short)f2bf(a.w);
  r[4] = (short)f2bf(b.x); r[5] = (short)f2bf(b.y);
  r[6] = (short)f2bf(b.z); r[7] = (short)f2bf(b.w);
  return r;
}

// ---------------------------------------------------------------------------
// R11 = R8 structure reverted (R9/R10 folds regressed, cause unattributable
// without per-kernel counters), plus two independently-argued deltas:
//  (a) kcf cache dropped (tier A was +504 MB net HBM traffic vs recompute);
//  (b) classifier fused into the final gemm_ln epilogue (removes cls_k).
// MFMA pipeline (16x16x32 bf16), fragment layouts HW-verified (m89).
// Per-layer WF layout (u16, 512/tile): tiles 0-47 Wq[kt*8+nt],
// 48-95 Wk^T[h*12+nt], 96-143 Wv[h*12+kt*2+nt], 144-175 Wo[kt*8+nt],
// 176-239 W1[kt*16+nt], 240-303 W2[kt*8+nt].  Layer stride 155,648 u16.
// ---------------------------------------------------------------------------

__global__ __launch_bounds__(256) void conv_w(
    const float* __restrict__ Wq, const float* __restrict__ Wk,
    const float* __restrict__ Wv, const float* __restrict__ Wo,
    const float* __restrict__ W1, const float* __restrict__ W2,
    unsigned short* __restrict__ WF) {
  int t = blockIdx.x;
  int l = t / 304, tt = t % 304;
#pragma unroll
  for (int e = 0; e < 2; ++e) {
    int idx = threadIdx.x * 2 + e;      // 0..511 element within tile
    int lane = idx >> 3, j = idx & 7;
    int wk = ((lane >> 4) << 3) + j;    // within-tile k 0..31
    int c16 = lane & 15;
    float v;
    if (tt < 48) {                      // Wq [192x128]
      int kt = tt >> 3, n2 = tt & 7;
      v = Wq[((size_t)l * CD + kt * 32 + wk) * HD + n2 * 16 + c16];
    } else if (tt < 96) {               // Wk^T per head [32x192]
      int t2 = tt - 48; int h = t2 / 12, n2 = t2 % 12;
      v = Wk[((size_t)l * CD + n2 * 16 + c16) * HD + h * 32 + wk];
    } else if (tt < 144) {              // Wv per head [192x32]
      int t2 = tt - 96; int h = t2 / 12, r2 = t2 % 12, kt = r2 >> 1, n2 = r2 & 1;
      v = Wv[((size_t)l * CD + kt * 32 + wk) * HD + h * 32 + n2 * 16 + c16];
    } else if (tt < 176) {              // Wo [128x128]
      int t2 = tt - 144; int kt = t2 >> 3, n2 = t2 & 7;
      v = Wo[((size_t)l * HD + kt * 32 + wk) * ND + n2 * 16 + c16];
    } else if (tt < 240) {              // W1 [128x256]
      int t2 = tt - 176; int kt = t2 >> 4, n2 = t2 & 15;
      v = W1[((size_t)l * ND + kt * 32 + wk) * (2 * ND) + n2 * 16 + c16];
    } else {                            // W2 [256x128]
      int t2 = tt - 240; int kt = t2 >> 3, n2 = t2 & 7;
      v = W2[((size_t)l * 2 * ND + kt * 32 + wk) * ND + n2 * 16 + c16];
    }
    WF[(size_t)l * 155648 + (size_t)tt * 512 + idx] = f2bf(v);
  }
}

__global__ __launch_bounds__(256) void prep_tq(
    const float* __restrict__ ntime, const float* __restrict__ tf,
    const float* __restrict__ tp, float* __restrict__ tqf) {
  int i = blockIdx.x * 256 + threadIdx.x;  // 0..6.4M
  int b = i >> 6, j = i & 63;
  tqf[i] = __cosf(ntime[b] * tf[j] + tp[j]);
}

__global__ __launch_bounds__(256) void prep_mb(const int* __restrict__ mask,
                                               unsigned* __restrict__ mb) {
  int e = blockIdx.x * 256 + threadIdx.x;
  if (e < BB) {
    unsigned m = 0;
    for (int n = 0; n < NN; ++n)
      m |= (mask[(size_t)e * NN + n] != 0 ? 1u : 0u) << n;
    mb[e] = m;
  }
}

// Generic 16-row-block GEMM. ABF: A bf16; OBF: out bf16 (f2bf at store ==
// f2bf at consumer load). A2 = f32 concat source for k >= ksplit.
template <int TN, int ABF, int OBF>
__global__ __launch_bounds__(256) void gemm16(
    const void* __restrict__ A, int lda,
    const float* __restrict__ A2, int lda2, int ksplit,
    const unsigned short* __restrict__ BF,
    int ktiles, int ntiles, int aKoffMul, int cColMul, int segBMul,
    const float* __restrict__ bias,
    void* __restrict__ C, int ldc, int relu) {
  const int tid = threadIdx.x;
  const int wv = tid >> 6, lane = tid & 63;
  const int NW = blockDim.x >> 6;
  const int m0 = blockIdx.x << 4;
  const int seg = blockIdx.y;
  const int arow = m0 + (lane & 15);
  const int kgrp = (lane >> 4) << 3;
  const int aK = seg * aKoffMul;
  const unsigned short* Bseg = BF + (size_t)seg * segBMul * 512;
  f32x4 acc[TN];
#pragma unroll
  for (int i = 0; i < TN; ++i) acc[i] = f32x4{0.f, 0.f, 0.f, 0.f};
  for (int kt = 0; kt < ktiles; ++kt) {
    bf16x8 af;
    if (kt * 32 >= ksplit) {
      af = load_a8(A2 + (size_t)arow * lda2 + (kt * 32 - ksplit) + kgrp);
    } else if (ABF) {
      af = *(const bf16x8*)((const unsigned short*)A + (size_t)arow * lda + aK +
                            kt * 32 + kgrp);
    } else {
      af = load_a8((const float*)A + (size_t)arow * lda + aK + kt * 32 + kgrp);
    }
#pragma unroll
    for (int i = 0; i < TN; ++i) {
      int nt = wv + NW * i;
      bf16x8 bf = *(const bf16x8*)(Bseg + (((size_t)(kt * ntiles + nt)) << 9) +
                                   (lane << 3));
      acc[i] = __builtin_amdgcn_mfma_f32_16x16x32_bf16(af, bf, acc[i], 0, 0, 0);
    }
  }
  const int crow = m0 + ((lane >> 4) << 2);
#pragma unroll
  for (int i = 0; i < TN; ++i) {
    int nt = wv + NW * i;
    int col = seg * cColMul + nt * 16 + (lane & 15);
    float bv = bias ? bias[col] : 0.f;
#pragma unroll
    for (int rr = 0; rr < 4; ++rr) {
      float v = acc[i][rr] + bv;
      if (relu) v = fmaxf(v, 0.f);
      if (OBF)
        ((unsigned short*)C)[(size_t)(crow + rr) * ldc + col] = f2bf(v);
      else
        ((float*)C)[(size_t)(crow + rr) * ldc + col] = v;
    }
  }
}

// GEMM (N=128) + bias + residual + LayerNorm -> xout f32. CLS=1: keep x in
// LDS and run the classifier (relu(x@Wc1+bc1)@Wc2+bc2 -> sigmoid) instead.
template <int ABF, int CLS>
__global__ __launch_bounds__(256) void gemm_ln(
    const void* __restrict__ A, int lda, int ktiles,
    const unsigned short* __restrict__ BF,
    const float* __restrict__ bias, const float* __restrict__ res,
    const float* __restrict__ gamma, const float* __restrict__ beta,
    float* __restrict__ xout,
    const float* __restrict__ Wc1, const float* __restrict__ bc1,
    const float* __restrict__ Wc2, const float* __restrict__ bc2,
    float* __restrict__ out) {
  __shared__ float Cs[16][132];
  __shared__ float hsh[CLS ? 16 : 1][64];
  const int tid = threadIdx.x;
  const int wv = tid >> 6, lane = tid & 63;
  const int m0 = blockIdx.x << 4;
  const int arow = m0 + (lane & 15);
  const int kgrp = (lane >> 4) << 3;
  const int nt0 = wv, nt1 = wv + 4;
  f32x4 acc0 = {0.f, 0.f, 0.f, 0.f}, acc1 = {0.f, 0.f, 0.f, 0.f};
  for (int kt = 0; kt < ktiles; ++kt) {
    bf16x8 af;
    if (ABF)
      af = *(const bf16x8*)((const unsigned short*)A + (size_t)arow * lda +
                            kt * 32 + kgrp);
    else
      af = load_a8((const float*)A + (size_t)arow * lda + kt * 32 + kgrp);
    bf16x8 b0 = *(const bf16x8*)(BF + (((size_t)(kt * 8 + nt0)) << 9) + (lane << 3));
    bf16x8 b1 = *(const bf16x8*)(BF + (((size_t)(kt * 8 + nt1)) << 9) + (lane << 3));
    acc0 = __builtin_amdgcn_mfma_f32_16x16x32_bf16(af, b0, acc0, 0, 0, 0);
    acc1 = __builtin_amdgcn_mfma_f32_16x16x32_bf16(af, b1, acc1, 0, 0, 0);
  }
  {
    const int lrow = (lane >> 4) << 2;
    int c0 = nt0 * 16 + (lane & 15), c1 = nt1 * 16 + (lane & 15);
    float bv0 = bias[c0], bv1 = bias[c1];
#pragma unroll
    for (int rr = 0; rr < 4; ++rr) {
      Cs[lrow + rr][c0] = acc0[rr] + bv0;
      Cs[lrow + rr][c1] = acc1[rr] + bv1;
    }
  }
  __syncthreads();
#pragma unroll
  for (int rr = 0; rr < 4; ++rr) {
    int rw = wv * 4 + rr;
    size_t grow = (size_t)(m0 + rw) * ND;
    float y0 = Cs[rw][lane] + res[grow + lane];
    float y1 = Cs[rw][lane + 64] + res[grow + lane + 64];
    float s = y0 + y1, ss = y0 * y0 + y1 * y1;
#pragma unroll
    for (int off = 32; off > 0; off >>= 1) {
      s += __shfl_xor(s, off);
      ss += __shfl_xor(ss, off);
    }
    float mean = s * (1.f / ND);
    float var = ss * (1.f / ND) - mean * mean;
    float rstd = rsqrtf(var + 1e-5f);
    float x0 = (y0 - mean) * rstd * gamma[lane] + beta[lane];
    float x1 = (y1 - mean) * rstd * gamma[lane + 64] + beta[lane + 64];
    if (CLS) {
      Cs[rw][lane] = x0;
      Cs[rw][lane + 64] = x1;
    } else {
      xout[grow + lane] = x0;
      xout[grow + lane + 64] = x1;
    }
  }
  if (CLS) {
    __syncthreads();
#pragma unroll
    for (int rep = 0; rep < 4; ++rep) {
      int idx = rep * 256 + tid;
      int row = idx >> 6, j = idx & 63;
      float a = 0.f;
      for (int c = 0; c < ND; ++c) a += Cs[row][c] * Wc1[c * 64 + j];
      hsh[row][j] = fmaxf(a + bc1[j], 0.f);
    }
    __syncthreads();
#pragma unroll
    for (int rr = 0; rr < 4; ++rr) {
      int row = wv * 4 + rr;
      float p = hsh[row][lane] * Wc2[lane];
#pragma unroll
      for (int off = 32; off > 0; off >>= 1) p += __shfl_xor(p, off);
      if (lane == 0)
        out[m0 + row] = 1.f / (1.f + expf(-(p + bc2[0])));
    }
  }
}

// Attention, 2 elements/block; kc computed in-kernel (nbf + cos time enc) —
// recompute beats caching (tier A's kcf was +504 MB net HBM traffic).
// r,u bf16; u aliases r (element-private; r staged to LDS first).
__global__ __launch_bounds__(256) void attn_b(
    const float* __restrict__ nbf, const float* __restrict__ nbt,
    const float* __restrict__ tf, const float* __restrict__ tp,
    const unsigned* __restrict__ mb, const unsigned short* __restrict__ r,
    unsigned short* __restrict__ u) {
  __shared__ __align__(16) unsigned short kcb[2][NN][200];
  __shared__ __align__(16) float rs[2][768];
  __shared__ __align__(16) float scs[2][NH][NN];
  __shared__ unsigned msks[2];
  const int tid = threadIdx.x;
  const size_t e0 = (size_t)blockIdx.x * 2;

  // stage r (bf16 -> f32 LDS): 1536 u16 = 192 x uint4
  if (tid < 192) {
    uint4 v = *(const uint4*)(r + e0 * 768 + tid * 8);
    const unsigned short* pv = (const unsigned short*)&v;
    float* dst = &rs[0][0] + tid * 8;
#pragma unroll
    for (int k = 0; k < 8; ++k) dst[k] = bf2f(pv[k]);
  }
  for (int i = tid; i < 2 * NN * 32; i += 256) {
    int el = i / (NN * 32), rem = i % (NN * 32);
    int n = rem >> 5, cq = rem & 31;
    float4 v = *(const float4*)&nbf[((e0 + el) * NN + n) * ND + cq * 4];
    ushort4 o;
    o.x = f2bf(v.x); o.y = f2bf(v.y); o.z = f2bf(v.z); o.w = f2bf(v.w);
    *(ushort4*)&kcb[el][n][cq * 4] = o;
  }
  for (int i = tid; i < 2 * NN * 32; i += 256) {
    int el = i / (NN * 32), rem = i % (NN * 32);
    int n = rem >> 5, jp = (rem & 31) * 2;
    float t = nbt[(e0 + el) * NN + n];
    unsigned a = f2bf(__cosf(t * tf[jp] + tp[jp]));
    unsigned b = f2bf(__cosf(t * tf[jp + 1] + tp[jp + 1]));
    *(unsigned*)&kcb[el][n][ND + jp] = a | (b << 16);
  }
  if (tid < 2) msks[tid] = mb[e0 + tid];
  __syncthreads();
  if (tid < 2 * NH * NN) {
    int el = tid / (NH * NN), rem = tid % (NH * NN);
    int h = rem / NN, n = rem % NN;
    const float* rp = &rs[el][h * CD];
    const unsigned short* kp = &kcb[el][n][0];
    float acc = 0.f;
    for (int c = 0; c < CD; c += 4) {
      float4 rv = *(const float4*)&rp[c];
      ushort4 kv = *(const ushort4*)&kp[c];
      acc += rv.x * bf2f(kv.x) + rv.y * bf2f(kv.y) + rv.z * bf2f(kv.z) +
             rv.w * bf2f(kv.w);
    }
    scs[el][h][n] =
        ((msks[el] >> n) & 1u) ? acc * 0.17677669529663687f : -1e9f;
  }
  __syncthreads();
  if (tid < 2 * NH) {
    int el = tid >> 2, h = tid & 3;
    float mx = -3.4e38f;
#pragma unroll
    for (int n = 0; n < NN; ++n) mx = fmaxf(mx, scs[el][h][n]);
    float ev[NN], s = 0.f;
#pragma unroll
    for (int n = 0; n < NN; ++n) { ev[n] = __expf(scs[el][h][n] - mx); s += ev[n]; }
    float inv = 1.f / s;
#pragma unroll
    for (int n = 0; n < NN; ++n) scs[el][h][n] = ev[n] * inv;
  }
  __syncthreads();
  for (int i = tid; i < 2 * NH * (CD / 4); i += 256) {  // 384 quads
    int el = i / (NH * 48), rem = i % (NH * 48);
    int h = rem / 48, cq = (rem % 48) * 4;
    float a0 = 0.f, a1 = 0.f, a2 = 0.f, a3 = 0.f;
#pragma unroll
    for (int n = 0; n < NN; ++n) {
      float w = scs[el][h][n];
      ushort4 kv = *(const ushort4*)&kcb[el][n][cq];
      a0 += w * bf2f(kv.x); a1 += w * bf2f(kv.y);
      a2 += w * bf2f(kv.z); a3 += w * bf2f(kv.w);
    }
    ushort4 o;
    o.x = f2bf(a0); o.y = f2bf(a1); o.z = f2bf(a2); o.w = f2bf(a3);
    *(ushort4*)&u[(e0 + el) * 768 + h * CD + cq] = o;
  }
}

// ---------------------------------------------------------------------------
// Tier C fallback (R5 fused kernel) if workspace is tiny.
// ---------------------------------------------------------------------------
#define G 2
#define T 256
#define KCS 196
#define RUS 772

__global__ __launch_bounds__(T, 4) void tgat_fused(
    const float* __restrict__ nf, const float* __restrict__ nbf,
    const float* __restrict__ nt, const float* __restrict__ nbt,
    const float* __restrict__ tf, const float* __restrict__ tp,
    const float* __restrict__ Wq, const float* __restrict__ bq,
    const float* __restrict__ Wk,
    const float* __restrict__ Wv, const float* __restrict__ bv,
    const float* __restrict__ Wo, const float* __restrict__ bo,
    const float* __restrict__ W1, const float* __restrict__ b1,
    const float* __restrict__ W2, const float* __restrict__ b2,
    const float* __restrict__ g1, const float* __restrict__ be1,
    const float* __restrict__ g2, const float* __restrict__ be2,
    const float* __restrict__ Wc1, const float* __restrict__ bc1,
    const float* __restrict__ Wc2, const float* __restrict__ bc2,
    const int* __restrict__ mask,
    float* __restrict__ out) {
  __shared__ __align__(16) unsigned short kc[G][NN][KCS];
  __shared__ __align__(16) float xs[G][ND];
  __shared__ __align__(16) float tqs[G][TD];
  __shared__ __align__(16) float ys[G][HD];
  __shared__ __align__(16) float rus[G][RUS];
  __shared__ __align__(16) float scs[G][NH][NN];
  __shared__ __align__(16) float h1s[G][2 * ND];
  __shared__ __align__(16) unsigned msks[G];
  float* asv = &h1s[0][0];
  const int tid = threadIdx.x;
  const int b0 = blockIdx.x * G;
  {
    int g = tid >> 7, j = tid & 127;
    xs[g][j] = nf[(b0 + g) * ND + j];
  }
  if (tid < G * TD) {
    int g = tid >> 6, j = tid & 63;
    tqs[g][j] = __cosf(nt[b0 + g] * tf[j] + tp[j]);
  }
  if (tid < G) {
    unsigned m = 0;
    for (int n = 0; n < NN; ++n)
      m |= (mask[(b0 + tid) * NN + n] != 0 ? 1u : 0u) << n;
    msks[tid] = m;
  }
  for (int idx = tid; idx < G * NN * (ND / 4); idx += T) {
    int g = idx / (NN * 32), rem = idx % (NN * 32);
    int n = rem >> 5, cq = rem & 31;
    float4 v = *(const float4*)&nbf[(((b0 + g) * NN + n) * ND) + cq * 4];
    ushort4 o;
    o.x = f2bf(v.x); o.y = f2bf(v.y); o.z = f2bf(v.z); o.w = f2bf(v.w);
    *(ushort4*)&kc[g][n][cq * 4] = o;
  }
  for (int idx = tid; idx < G * NN * TD; idx += T) {
    int g = idx / (NN * TD), rem = idx % (NN * TD);
    int n = rem >> 6, j = rem & 63;
    kc[g][n][ND + j] = f2bf(__cosf(nbt[(b0 + g) * NN + n] * tf[j] + tp[j]));
  }
  __syncthreads();
  const float scale = 0.17677669529663687f;
  for (int l = 0; l < NL; ++l) {
    {
      int g = tid >> 7, j = tid & 127;
      const float* wq = Wq + (l * CD) * HD + j;
      float acc = bq[l * HD + j];
      for (int c = 0; c < CD; c += 4) {
        float4 qv = (c < ND) ? *(const float4*)&xs[g][c]
                             : *(const float4*)&tqs[g][c - ND];
        acc += qv.x * wq[(c + 0) * HD] + qv.y * wq[(c + 1) * HD] +
               qv.z * wq[(c + 2) * HD] + qv.w * wq[(c + 3) * HD];
      }
      ys[g][j] = acc;
    }
    __syncthreads();
    for (int rep = 0; rep < 3; ++rep) {
      int i = rep * T + tid;
      int h = i / CD;
      int c2 = i - h * CD;
      const float* wk = Wk + (l * CD + c2) * HD + h * DH;
      const float* yp0 = &ys[0][h * DH];
      const float* yp1 = &ys[1][h * DH];
      float a0 = 0.f, a1 = 0.f;
#pragma unroll
      for (int d = 0; d < DH; d += 4) {
        float4 w4 = *(const float4*)&wk[d];
        float4 y0 = *(const float4*)&yp0[d];
        float4 y1 = *(const float4*)&yp1[d];
        a0 += y0.x * w4.x + y0.y * w4.y + y0.z * w4.z + y0.w * w4.w;
        a1 += y1.x * w4.x + y1.y * w4.y + y1.z * w4.z + y1.w * w4.w;
      }
      rus[0][i] = a0;
      rus[1][i] = a1;
    }
    __syncthreads();
    if (tid < G * NH * NN) {
      int g = tid / (NH * NN), rem = tid % (NH * NN);
      int h = rem / NN, n = rem % NN;
      const float* rp = &rus[g][h * CD];
      const unsigned short* kp = &kc[g][n][0];
      float acc = 0.f;
      for (int c = 0; c < CD; c += 4) {
        float4 rv = *(const float4*)&rp[c];
        ushort4 kv = *(const ushort4*)&kp[c];
        acc += rv.x * bf2f(kv.x) + rv.y * bf2f(kv.y) + rv.z * bf2f(kv.z) +
               rv.w * bf2f(kv.w);
      }
      scs[g][h][n] = ((msks[g] >> n) & 1u) ? acc * scale : -1e9f;
    }
    __syncthreads();
    if (tid < G * NH) {
      int g = tid / NH, h = tid % NH;
      float mx = -3.4e38f;
#pragma unroll
      for (int n = 0; n < NN; ++n) mx = fmaxf(mx, scs[g][h][n]);
      float ev[NN], s = 0.f;
#pragma unroll
      for (int n = 0; n < NN; ++n) { ev[n] = __expf(scs[g][h][n] - mx); s += ev[n]; }
      float inv = 1.f / s;
#pragma unroll
      for (int n = 0; n < NN; ++n) scs[g][h][n] = ev[n] * inv;
    }
    __syncthreads();
    for (int flat = tid; flat < G * NH * (CD / 4); flat += T) {
      int g = flat / (NH * 48), iq = flat % (NH * 48);
      int h = iq / 48, c = (iq % 48) * 4;
      const unsigned short* kp = &kc[g][0][0];
      float a0 = 0.f, a1 = 0.f, a2 = 0.f, a3 = 0.f;
#pragma unroll
      for (int n = 0; n < NN; ++n) {
        float w = scs[g][h][n];
        ushort4 kv = *(const ushort4*)&kp[n * KCS + c];
        a0 += w * bf2f(kv.x); a1 += w * bf2f(kv.y);
        a2 += w * bf2f(kv.z); a3 += w * bf2f(kv.w);
      }
      *(float4*)&rus[g][h * CD + c] = make_float4(a0, a1, a2, a3);
    }
    __syncthreads();
    {
      int j = tid & (HD - 1);
      int g = tid >> 7;
      int h = j >> 5;
      const float* wv = Wv + (l * CD) * HD + j;
      float acc = 0.f;
      for (int c = 0; c < CD; c += 4) {
        float4 uv = *(const float4*)&rus[g][h * CD + c];
        acc += uv.x * wv[(c + 0) * HD] + uv.y * wv[(c + 1) * HD] +
               uv.z * wv[(c + 2) * HD] + uv.w * wv[(c + 3) * HD];
      }
      asv[g * HD + j] = acc + bv[l * HD + j];
    }
    __syncthreads();
    {
      int j = tid & (ND - 1);
      int g = tid >> 7;
      const float* wo = Wo + (l * HD) * ND + j;
      float acc = 0.f;
      for (int c = 0; c < HD; c += 4) {
        float4 av = *(const float4*)&asv[g * HD + c];
        acc += av.x * wo[(c + 0) * ND] + av.y * wo[(c + 1) * ND] +
               av.z * wo[(c + 2) * ND] + av.w * wo[(c + 3) * ND];
      }
      rus[g][j] = acc + bo[l * ND + j];
    }
    __syncthreads();
    if (tid < G * 64) {
      int g = tid >> 6, lane = tid & 63;
      float y0 = xs[g][lane] + rus[g][lane];
      float y1 = xs[g][lane + 64] + rus[g][lane + 64];
      float s = y0 + y1, ss = y0 * y0 + y1 * y1;
#pragma unroll
      for (int off = 32; off > 0; off >>= 1) {
        s += __shfl_xor(s, off);
        ss += __shfl_xor(ss, off);
      }
      float mean = s * (1.f / ND);
      float var = ss * (1.f / ND) - mean * mean;
      float rstd = rsqrtf(var + 1e-5f);
      xs[g][lane] = (y0 - mean) * rstd * g1[l * ND + lane] + be1[l * ND + lane];
      xs[g][lane + 64] =
          (y1 - mean) * rstd * g1[l * ND + lane + 64] + be1[l * ND + lane + 64];
    }
    __syncthreads();
    {
      int j = tid;
      const float* w1p = W1 + (l * ND) * (2 * ND) + j;
      float acc0 = 0.f, acc1 = 0.f;
      for (int c = 0; c < ND; c += 4) {
        float w0 = w1p[(c + 0) * 2 * ND], wa = w1p[(c + 1) * 2 * ND],
              w2 = w1p[(c + 2) * 2 * ND], w3 = w1p[(c + 3) * 2 * ND];
        float4 x0 = *(const float4*)&xs[0][c];
        float4 x1 = *(const float4*)&xs[1][c];
        acc0 += x0.x * w0 + x0.y * wa + x0.z * w2 + x0.w * w3;
        acc1 += x1.x * w0 + x1.y * wa + x1.z * w2 + x1.w * w3;
      }
      float b1v = b1[l * 2 * ND + j];
      h1s[0][j] = fmaxf(acc0 + b1v, 0.f);
      h1s[1][j] = fmaxf(acc1 + b1v, 0.f);
    }
    __syncthreads();
    {
      int j = tid & (ND - 1);
      int g = tid >> 7;
      const float* w2p = W2 + (l * 2 * ND) * ND + j;
      float acc = 0.f;
      for (int c = 0; c < 2 * ND; c += 4) {
        float4 hv = *(const float4*)&h1s[g][c];
        acc += hv.x * w2p[(c + 0) * ND] + hv.y * w2p[(c + 1) * ND] +
               hv.z * w2p[(c + 2) * ND] + hv.w * w2p[(c + 3) * ND];
      }
      rus[g][j] = acc + b2[l * ND + j];
    }
    __syncthreads();
    if (tid < G * 64) {
      int g = tid >> 6, lane = tid & 63;
      float y0 = xs[g][lane] + rus[g][lane];
      float y1 = xs[g][lane + 64] + rus[g][lane + 64];
      float s = y0 + y1, ss = y0 * y0 + y1 * y1;
#pragma unroll
      for (int off = 32; off > 0; off >>= 1) {
        s += __shfl_xor(s, off);
        ss += __shfl_xor(ss, off);
      }
      float mean = s * (1.f / ND);
      float var = ss * (1.f / ND) - mean * mean;
      float rstd = rsqrtf(var + 1e-5f);
      xs[g][lane] = (y0 - mean) * rstd * g2[l * ND + lane] + be2[l * ND + lane];
      xs[g][lane + 64] =
          (y1 - mean) * rstd * g2[l * ND + lane + 64] + be2[l * ND + lane + 64];
    }
    __syncthreads();
  }
  if (tid < G * 64) {
    int j = tid & 63;
    int g = tid >> 6;
    const float* wc = Wc1 + j;
    float acc = 0.f;
    for (int c = 0; c < ND; c += 4) {
      float4 xv = *(const float4*)&xs[g][c];
      acc += xv.x * wc[(c + 0) * 64] + xv.y * wc[(c + 1) * 64] +
             xv.z * wc[(c + 2) * 64] + xv.w * wc[(c + 3) * 64];
    }
    ((float*)scs)[g * 64 + j] = fmaxf(acc + bc1[j], 0.f);
  }
  __syncthreads();
  if (tid < G * 64) {
    int g = tid >> 6, lane = tid & 63;
    float p = ((float*)scs)[g * 64 + lane] * Wc2[lane];
#pragma unroll
    for (int off = 32; off > 0; off >>= 1) p += __shfl_xor(p, off);
    if (lane == 0) {
      float z = p + bc2[0];
      out[b0 + g] = 1.f / (1.f + expf(-z));
    }
  }
}

extern "C" void kernel_launch(void* const* d_in, const int* in_sizes, int n_in,
                              void* d_out, int out_size, void* d_ws,
                              size_t ws_size, hipStream_t stream) {
  (void)in_sizes; (void)n_in; (void)out_size;
  const float* nf  = (const float*)d_in[0];
  const float* nbf = (const float*)d_in[1];
  const float* ntm = (const float*)d_in[2];
  const float* nbt = (const float*)d_in[3];
  const float* tf  = (const float*)d_in[4];
  const float* tp  = (const float*)d_in[5];
  const float* Wq  = (const float*)d_in[6];
  const float* bq  = (const float*)d_in[7];
  const float* Wk  = (const float*)d_in[8];
  // d_in[9] = bk: n-uniform score shift -> softmax-invariant -> dropped
  const float* Wv  = (const float*)d_in[10];
  const float* bv  = (const float*)d_in[11];
  const float* Wo  = (const float*)d_in[12];
  const float* bo  = (const float*)d_in[13];
  const float* W1  = (const float*)d_in[14];
  const float* b1  = (const float*)d_in[15];
  const float* W2  = (const float*)d_in[16];
  const float* b2  = (const float*)d_in[17];
  const float* g1  = (const float*)d_in[18];
  const float* be1 = (const float*)d_in[19];
  const float* g2  = (const float*)d_in[20];
  const float* be2 = (const float*)d_in[21];
  const float* Wc1 = (const float*)d_in[22];
  const float* bc1 = (const float*)d_in[23];
  const float* Wc2 = (const float*)d_in[24];
  const float* bc2 = (const float*)d_in[25];
  const int* mask  = (const int*)d_in[26];
  float* out = (float*)d_out;

  // Workspace (bytes) — R8 tier-B layout:
  //   WF      0 ..      622,592
  //   mb        .. + 400,000   =   1,022,592
  //   tqf       .. + 25.6M     =  26,622,592
  //   yb(bf16)  .. + 25.6M     =  52,222,592
  //   rb(bf16)  .. + 153.6M    = 205,822,592   (u aliases rb)
  //   ab(bf16)  .. + 25.6M     = 231,422,592
  //   h1b(bf16) .. + 51.2M     = 282,622,592
  //   xfb(f32)  .. + 51.2M     = 333,822,592   <- NEED
  const size_t NEED = 333822592ull;
  if (ws_size >= NEED) {
    char* w = (char*)d_ws;
    unsigned short* WF = (unsigned short*)w;
    unsigned* mb = (unsigned*)(w + 622592);
    float* tqf = (float*)(w + 1022592);
    unsigned short* yb = (unsigned short*)(w + 26622592);
    unsigned short* rb = (unsigned short*)(w + 52222592);
    unsigned short* ab = (unsigned short*)(w + 205822592);
    unsigned short* h1b = (unsigned short*)(w + 231422592);
    float* xfb = (float*)(w + 282622592);

    conv_w<<<608, 256, 0, stream>>>(Wq, Wk, Wv, Wo, W1, W2, WF);
    prep_tq<<<25000, 256, 0, stream>>>(ntm, tf, tp, tqf);
    prep_mb<<<(BB + 255) / 256, 256, 0, stream>>>(mask, mb);

    const float* xsrc = nf;
    for (int l = 0; l < NL; ++l) {
      const unsigned short* WFl = WF + (size_t)l * 155648;
      // y = [x|tq] @ Wq + bq  (bf16 out)
      gemm16<2, 0, 1><<<dim3(6250, 1), 256, 0, stream>>>(
          xsrc, ND, tqf, TD, 128, WFl, 6, 8, 0, 0, 0, bq + l * HD, yb, HD, 0);
      // r_h = y_h @ Wk_h^T  (bf16 in, bf16 out)
      gemm16<3, 1, 1><<<dim3(6250, 4), 256, 0, stream>>>(
          yb, HD, nullptr, 0, 1 << 30, WFl + 24576, 1, 12, DH, 192, 12,
          nullptr, rb, 768, 0);
      // scores/softmax/u (u bf16 overwrites r; kc recomputed in-kernel)
      attn_b<<<50000, 256, 0, stream>>>(nbf, nbt, tf, tp, mb, rb, rb);
      // a_h = u_h @ Wv_h + bv  (bf16 in, bf16 out)
      gemm16<1, 1, 1><<<dim3(6250, 4), 128, 0, stream>>>(
          rb, 768, nullptr, 0, 1 << 30, WFl + 49152, 6, 2, 192, DH, 12,
          bv + l * HD, ab, HD, 0);
      // x = LN1(x + a @ Wo + bo)
      gemm_ln<1, 0><<<6250, 256, 0, stream>>>(
          ab, HD, 4, WFl + 73728, bo + l * ND, xsrc, g1 + l * ND,
          be1 + l * ND, xfb, nullptr, nullptr, nullptr, nullptr, nullptr);
      // h1 = relu(x @ W1 + b1)  (bf16 out)
      gemm16<4, 0, 1><<<dim3(6250, 1), 256, 0, stream>>>(
          xfb, ND, nullptr, 0, 1 << 30, WFl + 90112, 4, 16, 0, 0, 0,
          b1 + l * 2 * ND, h1b, 2 * ND, 1);
      // x = LN2(x + h1 @ W2 + b2); final layer: classifier fused in epilogue
      if (l == NL - 1)
        gemm_ln<1, 1><<<6250, 256, 0, stream>>>(
            h1b, 2 * ND, 8, WFl + 122880, b2 + l * ND, xfb, g2 + l * ND,
            be2 + l * ND, xfb, Wc1, bc1, Wc2, bc2, out);
      else
        gemm_ln<1, 0><<<6250, 256, 0, stream>>>(
            h1b, 2 * ND, 8, WFl + 122880, b2 + l * ND, xfb, g2 + l * ND,
            be2 + l * ND, xfb, nullptr, nullptr, nullptr, nullptr, nullptr);
      xsrc = xfb;
    }
  } else {
    tgat_fused<<<BB / G, T, 0, stream>>>(nf, nbf, ntm, nbt, tf, tp, Wq, bq, Wk,
                                         Wv, bv, Wo, bo, W1, b1, W2, b2, g1,
                                         be1, g2, be2, Wc1, bc1, Wc2, bc2,
                                         mask, out);
  }
}

// Round 12
// 1287.709 us; speedup vs baseline: 1.3682x; 1.0908x over previous
//
#include <hip/hip_runtime.h>

#define BB 100000
#define NN 20
#define ND 128
#define TD 64
#define CD 192
#define HD 128
#define NH 4
#define DH 32
#define NL 2

typedef __attribute__((ext_vector_type(8))) short bf16x8;
typedef __attribute__((ext_vector_type(4))) float f32x4;

static __device__ __forceinline__ float bf2f(unsigned short u) {
  return __uint_as_float(((unsigned)u) << 16);
}
static __device__ __forceinline__ unsigned short f2bf(float x) {
  unsigned b = __float_as_uint(x);
  return (unsigned short)((b + 0x7FFFu + ((b >> 16) & 1u)) >> 16);
}
static __device__ __forceinline__ bf16x8 load_a8(const float* p) {
  float4 a = *(const float4*)p, b = *(const float4*)(p + 4);
  bf16x8 r;
  r[0] = (short)f2bf(a.x); r[1] = (short)f2bf(a.y);
  r[2] = (short)f2bf(a.z); r[3] = (short)f2bf(a.w);
  r[4] = (short)f2bf(b.x); r[5] = (short)f2bf(b.y);
  r[6] = (short)f2bf(b.z); r[7] = (short)f2bf(b.w);
  return r;
}

// ---------------------------------------------------------------------------
// R12 = R11 pipeline with GEMM phases fused through LDS (identical fragment
// math + rounding chain per phase; y and a become LDS tiles instead of HBM
// round trips; x stays in LDS between LN1 and FF1). 17 -> 11 dispatches,
// -410 MB HBM. attn_b / gemm_ln (LN2+cls) / preps unchanged from R11.
// WF layout (u16, 512/tile): 0-47 Wq[kt*8+nt], 48-95 Wk^T[h*12+nt],
// 96-143 Wv[h*12+kt*2+nt], 144-175 Wo[kt*8+nt], 176-239 W1[kt*16+nt],
// 240-303 W2[kt*8+nt]. Layer stride 155,648 u16.
// ---------------------------------------------------------------------------

__global__ __launch_bounds__(256) void conv_w(
    const float* __restrict__ Wq, const float* __restrict__ Wk,
    const float* __restrict__ Wv, const float* __restrict__ Wo,
    const float* __restrict__ W1, const float* __restrict__ W2,
    unsigned short* __restrict__ WF) {
  int t = blockIdx.x;
  int l = t / 304, tt = t % 304;
#pragma unroll
  for (int e = 0; e < 2; ++e) {
    int idx = threadIdx.x * 2 + e;      // 0..511 element within tile
    int lane = idx >> 3, j = idx & 7;
    int wk = ((lane >> 4) << 3) + j;    // within-tile k 0..31
    int c16 = lane & 15;
    float v;
    if (tt < 48) {                      // Wq [192x128]
      int kt = tt >> 3, n2 = tt & 7;
      v = Wq[((size_t)l * CD + kt * 32 + wk) * HD + n2 * 16 + c16];
    } else if (tt < 96) {               // Wk^T per head [32x192]
      int t2 = tt - 48; int h = t2 / 12, n2 = t2 % 12;
      v = Wk[((size_t)l * CD + n2 * 16 + c16) * HD + h * 32 + wk];
    } else if (tt < 144) {              // Wv per head [192x32]
      int t2 = tt - 96; int h = t2 / 12, r2 = t2 % 12, kt = r2 >> 1, n2 = r2 & 1;
      v = Wv[((size_t)l * CD + kt * 32 + wk) * HD + h * 32 + n2 * 16 + c16];
    } else if (tt < 176) {              // Wo [128x128]
      int t2 = tt - 144; int kt = t2 >> 3, n2 = t2 & 7;
      v = Wo[((size_t)l * HD + kt * 32 + wk) * ND + n2 * 16 + c16];
    } else if (tt < 240) {              // W1 [128x256]
      int t2 = tt - 176; int kt = t2 >> 4, n2 = t2 & 15;
      v = W1[((size_t)l * ND + kt * 32 + wk) * (2 * ND) + n2 * 16 + c16];
    } else {                            // W2 [256x128]
      int t2 = tt - 240; int kt = t2 >> 3, n2 = t2 & 7;
      v = W2[((size_t)l * 2 * ND + kt * 32 + wk) * ND + n2 * 16 + c16];
    }
    WF[(size_t)l * 155648 + (size_t)tt * 512 + idx] = f2bf(v);
  }
}

__global__ __launch_bounds__(256) void prep_tq(
    const float* __restrict__ ntime, const float* __restrict__ tf,
    const float* __restrict__ tp, float* __restrict__ tqf) {
  int i = blockIdx.x * 256 + threadIdx.x;  // 0..6.4M
  int b = i >> 6, j = i & 63;
  tqf[i] = __cosf(ntime[b] * tf[j] + tp[j]);
}

__global__ __launch_bounds__(256) void prep_mb(const int* __restrict__ mask,
                                               unsigned* __restrict__ mb) {
  int e = blockIdx.x * 256 + threadIdx.x;
  if (e < BB) {
    unsigned m = 0;
    for (int n = 0; n < NN; ++n)
      m |= (mask[(size_t)e * NN + n] != 0 ? 1u : 0u) << n;
    mb[e] = m;
  }
}

// Fused y+r: y = [x|tq]@Wq+bq (16x128, ->LDS bf16), then r_h = y_h@Wk_h^T.
// Wave = head in phase 2 (K=32, TN=12). Same rounding chain as R11's
// yb(bf16) round trip.
__global__ __launch_bounds__(256) void gemm_yr(
    const float* __restrict__ A, const float* __restrict__ tqf,
    const unsigned short* __restrict__ WFl, const float* __restrict__ bq,
    unsigned short* __restrict__ rb) {
  __shared__ unsigned short ylds[16][136];  // 136 u16 = 272 B rows, 16B-aligned
  const int tid = threadIdx.x;
  const int wv = tid >> 6, lane = tid & 63;
  const int m0 = blockIdx.x << 4;
  const int arow = m0 + (lane & 15);
  const int kgrp = (lane >> 4) << 3;
  // ---- phase 1: y ----
  {
    f32x4 acc[2];
    acc[0] = f32x4{0.f, 0.f, 0.f, 0.f};
    acc[1] = f32x4{0.f, 0.f, 0.f, 0.f};
    for (int kt = 0; kt < 6; ++kt) {
      bf16x8 af = (kt < 4)
                      ? load_a8(A + (size_t)arow * ND + kt * 32 + kgrp)
                      : load_a8(tqf + (size_t)arow * TD + (kt - 4) * 32 + kgrp);
#pragma unroll
      for (int i = 0; i < 2; ++i) {
        int nt = wv + 4 * i;
        bf16x8 bf = *(const bf16x8*)(WFl + (((size_t)(kt * 8 + nt)) << 9) +
                                     (lane << 3));
        acc[i] = __builtin_amdgcn_mfma_f32_16x16x32_bf16(af, bf, acc[i], 0, 0, 0);
      }
    }
    int lrow = (lane >> 4) << 2;
#pragma unroll
    for (int i = 0; i < 2; ++i) {
      int col = (wv + 4 * i) * 16 + (lane & 15);
      float bv = bq[col];
#pragma unroll
      for (int rr = 0; rr < 4; ++rr)
        ylds[lrow + rr][col] = f2bf(acc[i][rr] + bv);
    }
  }
  __syncthreads();
  // ---- phase 2: r_h (wave wv = head), K=32, 12 n-tiles ----
  {
    f32x4 acc[12];
#pragma unroll
    for (int i = 0; i < 12; ++i) acc[i] = f32x4{0.f, 0.f, 0.f, 0.f};
    bf16x8 af = *(const bf16x8*)&ylds[lane & 15][wv * 32 + kgrp];
    const unsigned short* B = WFl + 24576 + (size_t)wv * 12 * 512;
#pragma unroll
    for (int i = 0; i < 12; ++i) {
      bf16x8 bf = *(const bf16x8*)(B + (((size_t)i) << 9) + (lane << 3));
      acc[i] = __builtin_amdgcn_mfma_f32_16x16x32_bf16(af, bf, acc[i], 0, 0, 0);
    }
    int crow = m0 + ((lane >> 4) << 2);
#pragma unroll
    for (int i = 0; i < 12; ++i) {
      int col = wv * 192 + i * 16 + (lane & 15);
#pragma unroll
      for (int rr = 0; rr < 4; ++rr)
        rb[(size_t)(crow + rr) * 768 + col] = f2bf(acc[i][rr]);
    }
  }
}

// Fused a + (attn@Wo + bo + res + LN1) + FF1.  Phase 1: a_h = u_h@Wv_h+bv
// (wave=head) -> LDS bf16 (same bits as R11's ab round trip). Phase 2:
// gemm_ln body (A = a_lds). Phase 3: FF1 from x in LDS (f2bf at load ==
// R11's load_a8 from xfb). Writes xfb (LN2 residual) and h1b.
__global__ __launch_bounds__(256) void gemm_aln1ff1(
    const unsigned short* __restrict__ u, const unsigned short* __restrict__ WFl,
    const float* __restrict__ bv, const float* __restrict__ bo,
    const float* __restrict__ res, const float* __restrict__ gamma,
    const float* __restrict__ beta, const float* __restrict__ b1,
    float* __restrict__ xout, unsigned short* __restrict__ h1b) {
  __shared__ unsigned short alds[16][136];
  __shared__ float Cs[16][132];
  const int tid = threadIdx.x;
  const int wv = tid >> 6, lane = tid & 63;
  const int m0 = blockIdx.x << 4;
  const int arow = m0 + (lane & 15);
  const int kgrp = (lane >> 4) << 3;
  // ---- phase 1: a_h (wave = head), K=192, 2 n-tiles ----
  {
    f32x4 acc0 = {0.f, 0.f, 0.f, 0.f}, acc1 = {0.f, 0.f, 0.f, 0.f};
    const unsigned short* B = WFl + 49152 + (size_t)wv * 12 * 512;
    for (int kt = 0; kt < 6; ++kt) {
      bf16x8 af = *(const bf16x8*)(u + (size_t)arow * 768 + wv * 192 +
                                   kt * 32 + kgrp);
      bf16x8 b0 = *(const bf16x8*)(B + (((size_t)(kt * 2 + 0)) << 9) + (lane << 3));
      bf16x8 b1f = *(const bf16x8*)(B + (((size_t)(kt * 2 + 1)) << 9) + (lane << 3));
      acc0 = __builtin_amdgcn_mfma_f32_16x16x32_bf16(af, b0, acc0, 0, 0, 0);
      acc1 = __builtin_amdgcn_mfma_f32_16x16x32_bf16(af, b1f, acc1, 0, 0, 0);
    }
    int lrow = (lane >> 4) << 2;
    int c0 = wv * 32 + (lane & 15), c1 = wv * 32 + 16 + (lane & 15);
    float bv0 = bv[c0], bv1 = bv[c1];
#pragma unroll
    for (int rr = 0; rr < 4; ++rr) {
      alds[lrow + rr][c0] = f2bf(acc0[rr] + bv0);
      alds[lrow + rr][c1] = f2bf(acc1[rr] + bv1);
    }
  }
  __syncthreads();
  // ---- phase 2: attnout = a@Wo + bo; +res; LN1 -> Cs(f32) + xout ----
  {
    const int nt0 = wv, nt1 = wv + 4;
    f32x4 acc0 = {0.f, 0.f, 0.f, 0.f}, acc1 = {0.f, 0.f, 0.f, 0.f};
    for (int kt = 0; kt < 4; ++kt) {
      bf16x8 af = *(const bf16x8*)&alds[lane & 15][kt * 32 + kgrp];
      bf16x8 b0 = *(const bf16x8*)(WFl + 73728 +
                                   (((size_t)(kt * 8 + nt0)) << 9) + (lane << 3));
      bf16x8 b1f = *(const bf16x8*)(WFl + 73728 +
                                    (((size_t)(kt * 8 + nt1)) << 9) + (lane << 3));
      acc0 = __builtin_amdgcn_mfma_f32_16x16x32_bf16(af, b0, acc0, 0, 0, 0);
      acc1 = __builtin_amdgcn_mfma_f32_16x16x32_bf16(af, b1f, acc1, 0, 0, 0);
    }
    {
      int lrow = (lane >> 4) << 2;
      int c0 = nt0 * 16 + (lane & 15), c1 = nt1 * 16 + (lane & 15);
      float bv0 = bo[c0], bv1 = bo[c1];
#pragma unroll
      for (int rr = 0; rr < 4; ++rr) {
        Cs[lrow + rr][c0] = acc0[rr] + bv0;
        Cs[lrow + rr][c1] = acc1[rr] + bv1;
      }
    }
    __syncthreads();
#pragma unroll
    for (int rr = 0; rr < 4; ++rr) {
      int rw = wv * 4 + rr;
      size_t grow = (size_t)(m0 + rw) * ND;
      float y0 = Cs[rw][lane] + res[grow + lane];
      float y1 = Cs[rw][lane + 64] + res[grow + lane + 64];
      float s = y0 + y1, ss = y0 * y0 + y1 * y1;
#pragma unroll
      for (int off = 32; off > 0; off >>= 1) {
        s += __shfl_xor(s, off);
        ss += __shfl_xor(ss, off);
      }
      float mean = s * (1.f / ND);
      float var = ss * (1.f / ND) - mean * mean;
      float rstd = rsqrtf(var + 1e-5f);
      float x0 = (y0 - mean) * rstd * gamma[lane] + beta[lane];
      float x1 = (y1 - mean) * rstd * gamma[lane + 64] + beta[lane + 64];
      xout[grow + lane] = x0;
      xout[grow + lane + 64] = x1;
      Cs[rw][lane] = x0;
      Cs[rw][lane + 64] = x1;
    }
  }
  __syncthreads();
  // ---- phase 3: h1 = relu(x @ W1 + b1) -> h1b bf16 ----
  {
    f32x4 acc[4];
#pragma unroll
    for (int i = 0; i < 4; ++i) acc[i] = f32x4{0.f, 0.f, 0.f, 0.f};
    for (int kt = 0; kt < 4; ++kt) {
      bf16x8 af = load_a8(&Cs[lane & 15][kt * 32 + kgrp]);
#pragma unroll
      for (int i = 0; i < 4; ++i) {
        int nt = wv + 4 * i;
        bf16x8 bf = *(const bf16x8*)(WFl + 90112 +
                                     (((size_t)(kt * 16 + nt)) << 9) + (lane << 3));
        acc[i] = __builtin_amdgcn_mfma_f32_16x16x32_bf16(af, bf, acc[i], 0, 0, 0);
      }
    }
    int crow = m0 + ((lane >> 4) << 2);
#pragma unroll
    for (int i = 0; i < 4; ++i) {
      int col = (wv + 4 * i) * 16 + (lane & 15);
      float bvv = b1[col];
#pragma unroll
      for (int rr = 0; rr < 4; ++rr)
        h1b[(size_t)(crow + rr) * (2 * ND) + col] =
            f2bf(fmaxf(acc[i][rr] + bvv, 0.f));
    }
  }
}

// GEMM (N=128) + bias + residual + LayerNorm -> xout f32. CLS=1: keep x in
// LDS and run the classifier (relu(x@Wc1+bc1)@Wc2+bc2 -> sigmoid) instead.
template <int ABF, int CLS>
__global__ __launch_bounds__(256) void gemm_ln(
    const void* __restrict__ A, int lda, int ktiles,
    const unsigned short* __restrict__ BF,
    const float* __restrict__ bias, const float* __restrict__ res,
    const float* __restrict__ gamma, const float* __restrict__ beta,
    float* __restrict__ xout,
    const float* __restrict__ Wc1, const float* __restrict__ bc1,
    const float* __restrict__ Wc2, const float* __restrict__ bc2,
    float* __restrict__ out) {
  __shared__ float Cs[16][132];
  __shared__ float hsh[CLS ? 16 : 1][64];
  const int tid = threadIdx.x;
  const int wv = tid >> 6, lane = tid & 63;
  const int m0 = blockIdx.x << 4;
  const int arow = m0 + (lane & 15);
  const int kgrp = (lane >> 4) << 3;
  const int nt0 = wv, nt1 = wv + 4;
  f32x4 acc0 = {0.f, 0.f, 0.f, 0.f}, acc1 = {0.f, 0.f, 0.f, 0.f};
  for (int kt = 0; kt < ktiles; ++kt) {
    bf16x8 af;
    if (ABF)
      af = *(const bf16x8*)((const unsigned short*)A + (size_t)arow * lda +
                            kt * 32 + kgrp);
    else
      af = load_a8((const float*)A + (size_t)arow * lda + kt * 32 + kgrp);
    bf16x8 b0 = *(const bf16x8*)(BF + (((size_t)(kt * 8 + nt0)) << 9) + (lane << 3));
    bf16x8 b1 = *(const bf16x8*)(BF + (((size_t)(kt * 8 + nt1)) << 9) + (lane << 3));
    acc0 = __builtin_amdgcn_mfma_f32_16x16x32_bf16(af, b0, acc0, 0, 0, 0);
    acc1 = __builtin_amdgcn_mfma_f32_16x16x32_bf16(af, b1, acc1, 0, 0, 0);
  }
  {
    const int lrow = (lane >> 4) << 2;
    int c0 = nt0 * 16 + (lane & 15), c1 = nt1 * 16 + (lane & 15);
    float bv0 = bias[c0], bv1 = bias[c1];
#pragma unroll
    for (int rr = 0; rr < 4; ++rr) {
      Cs[lrow + rr][c0] = acc0[rr] + bv0;
      Cs[lrow + rr][c1] = acc1[rr] + bv1;
    }
  }
  __syncthreads();
#pragma unroll
  for (int rr = 0; rr < 4; ++rr) {
    int rw = wv * 4 + rr;
    size_t grow = (size_t)(m0 + rw) * ND;
    float y0 = Cs[rw][lane] + res[grow + lane];
    float y1 = Cs[rw][lane + 64] + res[grow + lane + 64];
    float s = y0 + y1, ss = y0 * y0 + y1 * y1;
#pragma unroll
    for (int off = 32; off > 0; off >>= 1) {
      s += __shfl_xor(s, off);
      ss += __shfl_xor(ss, off);
    }
    float mean = s * (1.f / ND);
    float var = ss * (1.f / ND) - mean * mean;
    float rstd = rsqrtf(var + 1e-5f);
    float x0 = (y0 - mean) * rstd * gamma[lane] + beta[lane];
    float x1 = (y1 - mean) * rstd * gamma[lane + 64] + beta[lane + 64];
    if (CLS) {
      Cs[rw][lane] = x0;
      Cs[rw][lane + 64] = x1;
    } else {
      xout[grow + lane] = x0;
      xout[grow + lane + 64] = x1;
    }
  }
  if (CLS) {
    __syncthreads();
#pragma unroll
    for (int rep = 0; rep < 4; ++rep) {
      int idx = rep * 256 + tid;
      int row = idx >> 6, j = idx & 63;
      float a = 0.f;
      for (int c = 0; c < ND; ++c) a += Cs[row][c] * Wc1[c * 64 + j];
      hsh[row][j] = fmaxf(a + bc1[j], 0.f);
    }
    __syncthreads();
#pragma unroll
    for (int rr = 0; rr < 4; ++rr) {
      int row = wv * 4 + rr;
      float p = hsh[row][lane] * Wc2[lane];
#pragma unroll
      for (int off = 32; off > 0; off >>= 1) p += __shfl_xor(p, off);
      if (lane == 0)
        out[m0 + row] = 1.f / (1.f + expf(-(p + bc2[0])));
    }
  }
}

// Attention, 2 elements/block; kc computed in-kernel. r,u bf16; u aliases r
// (element-private; r staged to LDS first). Unchanged from R11.
__global__ __launch_bounds__(256) void attn_b(
    const float* __restrict__ nbf, const float* __restrict__ nbt,
    const float* __restrict__ tf, const float* __restrict__ tp,
    const unsigned* __restrict__ mb, const unsigned short* __restrict__ r,
    unsigned short* __restrict__ u) {
  __shared__ __align__(16) unsigned short kcb[2][NN][200];
  __shared__ __align__(16) float rs[2][768];
  __shared__ __align__(16) float scs[2][NH][NN];
  __shared__ unsigned msks[2];
  const int tid = threadIdx.x;
  const size_t e0 = (size_t)blockIdx.x * 2;

  if (tid < 192) {
    uint4 v = *(const uint4*)(r + e0 * 768 + tid * 8);
    const unsigned short* pv = (const unsigned short*)&v;
    float* dst = &rs[0][0] + tid * 8;
#pragma unroll
    for (int k = 0; k < 8; ++k) dst[k] = bf2f(pv[k]);
  }
  for (int i = tid; i < 2 * NN * 32; i += 256) {
    int el = i / (NN * 32), rem = i % (NN * 32);
    int n = rem >> 5, cq = rem & 31;
    float4 v = *(const float4*)&nbf[((e0 + el) * NN + n) * ND + cq * 4];
    ushort4 o;
    o.x = f2bf(v.x); o.y = f2bf(v.y); o.z = f2bf(v.z); o.w = f2bf(v.w);
    *(ushort4*)&kcb[el][n][cq * 4] = o;
  }
  for (int i = tid; i < 2 * NN * 32; i += 256) {
    int el = i / (NN * 32), rem = i % (NN * 32);
    int n = rem >> 5, jp = (rem & 31) * 2;
    float t = nbt[(e0 + el) * NN + n];
    unsigned a = f2bf(__cosf(t * tf[jp] + tp[jp]));
    unsigned b = f2bf(__cosf(t * tf[jp + 1] + tp[jp + 1]));
    *(unsigned*)&kcb[el][n][ND + jp] = a | (b << 16);
  }
  if (tid < 2) msks[tid] = mb[e0 + tid];
  __syncthreads();
  if (tid < 2 * NH * NN) {
    int el = tid / (NH * NN), rem = tid % (NH * NN);
    int h = rem / NN, n = rem % NN;
    const float* rp = &rs[el][h * CD];
    const unsigned short* kp = &kcb[el][n][0];
    float acc = 0.f;
    for (int c = 0; c < CD; c += 4) {
      float4 rv = *(const float4*)&rp[c];
      ushort4 kv = *(const ushort4*)&kp[c];
      acc += rv.x * bf2f(kv.x) + rv.y * bf2f(kv.y) + rv.z * bf2f(kv.z) +
             rv.w * bf2f(kv.w);
    }
    scs[el][h][n] =
        ((msks[el] >> n) & 1u) ? acc * 0.17677669529663687f : -1e9f;
  }
  __syncthreads();
  if (tid < 2 * NH) {
    int el = tid >> 2, h = tid & 3;
    float mx = -3.4e38f;
#pragma unroll
    for (int n = 0; n < NN; ++n) mx = fmaxf(mx, scs[el][h][n]);
    float ev[NN], s = 0.f;
#pragma unroll
    for (int n = 0; n < NN; ++n) { ev[n] = __expf(scs[el][h][n] - mx); s += ev[n]; }
    float inv = 1.f / s;
#pragma unroll
    for (int n = 0; n < NN; ++n) scs[el][h][n] = ev[n] * inv;
  }
  __syncthreads();
  for (int i = tid; i < 2 * NH * (CD / 4); i += 256) {  // 384 quads
    int el = i / (NH * 48), rem = i % (NH * 48);
    int h = rem / 48, cq = (rem % 48) * 4;
    float a0 = 0.f, a1 = 0.f, a2 = 0.f, a3 = 0.f;
#pragma unroll
    for (int n = 0; n < NN; ++n) {
      float w = scs[el][h][n];
      ushort4 kv = *(const ushort4*)&kcb[el][n][cq];
      a0 += w * bf2f(kv.x); a1 += w * bf2f(kv.y);
      a2 += w * bf2f(kv.z); a3 += w * bf2f(kv.w);
    }
    ushort4 o;
    o.x = f2bf(a0); o.y = f2bf(a1); o.z = f2bf(a2); o.w = f2bf(a3);
    *(ushort4*)&u[(e0 + el) * 768 + h * CD + cq] = o;
  }
}

// ---------------------------------------------------------------------------
// Tier C fallback (R5 fused kernel) if workspace is tiny.
// ---------------------------------------------------------------------------
#define G 2
#define T 256
#define KCS 196
#define RUS 772

__global__ __launch_bounds__(T, 4) void tgat_fused(
    const float* __restrict__ nf, const float* __restrict__ nbf,
    const float* __restrict__ nt, const float* __restrict__ nbt,
    const float* __restrict__ tf, const float* __restrict__ tp,
    const float* __restrict__ Wq, const float* __restrict__ bq,
    const float* __restrict__ Wk,
    const float* __restrict__ Wv, const float* __restrict__ bv,
    const float* __restrict__ Wo, const float* __restrict__ bo,
    const float* __restrict__ W1, const float* __restrict__ b1,
    const float* __restrict__ W2, const float* __restrict__ b2,
    const float* __restrict__ g1, const float* __restrict__ be1,
    const float* __restrict__ g2, const float* __restrict__ be2,
    const float* __restrict__ Wc1, const float* __restrict__ bc1,
    const float* __restrict__ Wc2, const float* __restrict__ bc2,
    const int* __restrict__ mask,
    float* __restrict__ out) {
  __shared__ __align__(16) unsigned short kc[G][NN][KCS];
  __shared__ __align__(16) float xs[G][ND];
  __shared__ __align__(16) float tqs[G][TD];
  __shared__ __align__(16) float ys[G][HD];
  __shared__ __align__(16) float rus[G][RUS];
  __shared__ __align__(16) float scs[G][NH][NN];
  __shared__ __align__(16) float h1s[G][2 * ND];
  __shared__ __align__(16) unsigned msks[G];
  float* asv = &h1s[0][0];
  const int tid = threadIdx.x;
  const int b0 = blockIdx.x * G;
  {
    int g = tid >> 7, j = tid & 127;
    xs[g][j] = nf[(b0 + g) * ND + j];
  }
  if (tid < G * TD) {
    int g = tid >> 6, j = tid & 63;
    tqs[g][j] = __cosf(nt[b0 + g] * tf[j] + tp[j]);
  }
  if (tid < G) {
    unsigned m = 0;
    for (int n = 0; n < NN; ++n)
      m |= (mask[(b0 + tid) * NN + n] != 0 ? 1u : 0u) << n;
    msks[tid] = m;
  }
  for (int idx = tid; idx < G * NN * (ND / 4); idx += T) {
    int g = idx / (NN * 32), rem = idx % (NN * 32);
    int n = rem >> 5, cq = rem & 31;
    float4 v = *(const float4*)&nbf[(((b0 + g) * NN + n) * ND) + cq * 4];
    ushort4 o;
    o.x = f2bf(v.x); o.y = f2bf(v.y); o.z = f2bf(v.z); o.w = f2bf(v.w);
    *(ushort4*)&kc[g][n][cq * 4] = o;
  }
  for (int idx = tid; idx < G * NN * TD; idx += T) {
    int g = idx / (NN * TD), rem = idx % (NN * TD);
    int n = rem >> 6, j = rem & 63;
    kc[g][n][ND + j] = f2bf(__cosf(nbt[(b0 + g) * NN + n] * tf[j] + tp[j]));
  }
  __syncthreads();
  const float scale = 0.17677669529663687f;
  for (int l = 0; l < NL; ++l) {
    {
      int g = tid >> 7, j = tid & 127;
      const float* wq = Wq + (l * CD) * HD + j;
      float acc = bq[l * HD + j];
      for (int c = 0; c < CD; c += 4) {
        float4 qv = (c < ND) ? *(const float4*)&xs[g][c]
                             : *(const float4*)&tqs[g][c - ND];
        acc += qv.x * wq[(c + 0) * HD] + qv.y * wq[(c + 1) * HD] +
               qv.z * wq[(c + 2) * HD] + qv.w * wq[(c + 3) * HD];
      }
      ys[g][j] = acc;
    }
    __syncthreads();
    for (int rep = 0; rep < 3; ++rep) {
      int i = rep * T + tid;
      int h = i / CD;
      int c2 = i - h * CD;
      const float* wk = Wk + (l * CD + c2) * HD + h * DH;
      const float* yp0 = &ys[0][h * DH];
      const float* yp1 = &ys[1][h * DH];
      float a0 = 0.f, a1 = 0.f;
#pragma unroll
      for (int d = 0; d < DH; d += 4) {
        float4 w4 = *(const float4*)&wk[d];
        float4 y0 = *(const float4*)&yp0[d];
        float4 y1 = *(const float4*)&yp1[d];
        a0 += y0.x * w4.x + y0.y * w4.y + y0.z * w4.z + y0.w * w4.w;
        a1 += y1.x * w4.x + y1.y * w4.y + y1.z * w4.z + y1.w * w4.w;
      }
      rus[0][i] = a0;
      rus[1][i] = a1;
    }
    __syncthreads();
    if (tid < G * NH * NN) {
      int g = tid / (NH * NN), rem = tid % (NH * NN);
      int h = rem / NN, n = rem % NN;
      const float* rp = &rus[g][h * CD];
      const unsigned short* kp = &kc[g][n][0];
      float acc = 0.f;
      for (int c = 0; c < CD; c += 4) {
        float4 rv = *(const float4*)&rp[c];
        ushort4 kv = *(const ushort4*)&kp[c];
        acc += rv.x * bf2f(kv.x) + rv.y * bf2f(kv.y) + rv.z * bf2f(kv.z) +
               rv.w * bf2f(kv.w);
      }
      scs[g][h][n] = ((msks[g] >> n) & 1u) ? acc * scale : -1e9f;
    }
    __syncthreads();
    if (tid < G * NH) {
      int g = tid / NH, h = tid % NH;
      float mx = -3.4e38f;
#pragma unroll
      for (int n = 0; n < NN; ++n) mx = fmaxf(mx, scs[g][h][n]);
      float ev[NN], s = 0.f;
#pragma unroll
      for (int n = 0; n < NN; ++n) { ev[n] = __expf(scs[g][h][n] - mx); s += ev[n]; }
      float inv = 1.f / s;
#pragma unroll
      for (int n = 0; n < NN; ++n) scs[g][h][n] = ev[n] * inv;
    }
    __syncthreads();
    for (int flat = tid; flat < G * NH * (CD / 4); flat += T) {
      int g = flat / (NH * 48), iq = flat % (NH * 48);
      int h = iq / 48, c = (iq % 48) * 4;
      const unsigned short* kp = &kc[g][0][0];
      float a0 = 0.f, a1 = 0.f, a2 = 0.f, a3 = 0.f;
#pragma unroll
      for (int n = 0; n < NN; ++n) {
        float w = scs[g][h][n];
        ushort4 kv = *(const ushort4*)&kp[n * KCS + c];
        a0 += w * bf2f(kv.x); a1 += w * bf2f(kv.y);
        a2 += w * bf2f(kv.z); a3 += w * bf2f(kv.w);
      }
      *(float4*)&rus[g][h * CD + c] = make_float4(a0, a1, a2, a3);
    }
    __syncthreads();
    {
      int j = tid & (HD - 1);
      int g = tid >> 7;
      int h = j >> 5;
      const float* wv = Wv + (l * CD) * HD + j;
      float acc = 0.f;
      for (int c = 0; c < CD; c += 4) {
        float4 uv = *(const float4*)&rus[g][h * CD + c];
        acc += uv.x * wv[(c + 0) * HD] + uv.y * wv[(c + 1) * HD] +
               uv.z * wv[(c + 2) * HD] + uv.w * wv[(c + 3) * HD];
      }
      asv[g * HD + j] = acc + bv[l * HD + j];
    }
    __syncthreads();
    {
      int j = tid & (ND - 1);
      int g = tid >> 7;
      const float* wo = Wo + (l * HD) * ND + j;
      float acc = 0.f;
      for (int c = 0; c < HD; c += 4) {
        float4 av = *(const float4*)&asv[g * HD + c];
        acc += av.x * wo[(c + 0) * ND] + av.y * wo[(c + 1) * ND] +
               av.z * wo[(c + 2) * ND] + av.w * wo[(c + 3) * ND];
      }
      rus[g][j] = acc + bo[l * ND + j];
    }
    __syncthreads();
    if (tid < G * 64) {
      int g = tid >> 6, lane = tid & 63;
      float y0 = xs[g][lane] + rus[g][lane];
      float y1 = xs[g][lane + 64] + rus[g][lane + 64];
      float s = y0 + y1, ss = y0 * y0 + y1 * y1;
#pragma unroll
      for (int off = 32; off > 0; off >>= 1) {
        s += __shfl_xor(s, off);
        ss += __shfl_xor(ss, off);
      }
      float mean = s * (1.f / ND);
      float var = ss * (1.f / ND) - mean * mean;
      float rstd = rsqrtf(var + 1e-5f);
      xs[g][lane] = (y0 - mean) * rstd * g1[l * ND + lane] + be1[l * ND + lane];
      xs[g][lane + 64] =
          (y1 - mean) * rstd * g1[l * ND + lane + 64] + be1[l * ND + lane + 64];
    }
    __syncthreads();
    {
      int j = tid;
      const float* w1p = W1 + (l * ND) * (2 * ND) + j;
      float acc0 = 0.f, acc1 = 0.f;
      for (int c = 0; c < ND; c += 4) {
        float w0 = w1p[(c + 0) * 2 * ND], wa = w1p[(c + 1) * 2 * ND],
              w2 = w1p[(c + 2) * 2 * ND], w3 = w1p[(c + 3) * 2 * ND];
        float4 x0 = *(const float4*)&xs[0][c];
        float4 x1 = *(const float4*)&xs[1][c];
        acc0 += x0.x * w0 + x0.y * wa + x0.z * w2 + x0.w * w3;
        acc1 += x1.x * w0 + x1.y * wa + x1.z * w2 + x1.w * w3;
      }
      float b1v = b1[l * 2 * ND + j];
      h1s[0][j] = fmaxf(acc0 + b1v, 0.f);
      h1s[1][j] = fmaxf(acc1 + b1v, 0.f);
    }
    __syncthreads();
    {
      int j = tid & (ND - 1);
      int g = tid >> 7;
      const float* w2p = W2 + (l * 2 * ND) * ND + j;
      float acc = 0.f;
      for (int c = 0; c < 2 * ND; c += 4) {
        float4 hv = *(const float4*)&h1s[g][c];
        acc += hv.x * w2p[(c + 0) * ND] + hv.y * w2p[(c + 1) * ND] +
               hv.z * w2p[(c + 2) * ND] + hv.w * w2p[(c + 3) * ND];
      }
      rus[g][j] = acc + b2[l * ND + j];
    }
    __syncthreads();
    if (tid < G * 64) {
      int g = tid >> 6, lane = tid & 63;
      float y0 = xs[g][lane] + rus[g][lane];
      float y1 = xs[g][lane + 64] + rus[g][lane + 64];
      float s = y0 + y1, ss = y0 * y0 + y1 * y1;
#pragma unroll
      for (int off = 32; off > 0; off >>= 1) {
        s += __shfl_xor(s, off);
        ss += __shfl_xor(ss, off);
      }
      float mean = s * (1.f / ND);
      float var = ss * (1.f / ND) - mean * mean;
      float rstd = rsqrtf(var + 1e-5f);
      xs[g][lane] = (y0 - mean) * rstd * g2[l * ND + lane] + be2[l * ND + lane];
      xs[g][lane + 64] =
          (y1 - mean) * rstd * g2[l * ND + lane + 64] + be2[l * ND + lane + 64];
    }
    __syncthreads();
  }
  if (tid < G * 64) {
    int j = tid & 63;
    int g = tid >> 6;
    const float* wc = Wc1 + j;
    float acc = 0.f;
    for (int c = 0; c < ND; c += 4) {
      float4 xv = *(const float4*)&xs[g][c];
      acc += xv.x * wc[(c + 0) * 64] + xv.y * wc[(c + 1) * 64] +
             xv.z * wc[(c + 2) * 64] + xv.w * wc[(c + 3) * 64];
    }
    ((float*)scs)[g * 64 + j] = fmaxf(acc + bc1[j], 0.f);
  }
  __syncthreads();
  if (tid < G * 64) {
    int g = tid >> 6, lane = tid & 63;
    float p = ((float*)scs)[g * 64 + lane] * Wc2[lane];
#pragma unroll
    for (int off = 32; off > 0; off >>= 1) p += __shfl_xor(p, off);
    if (lane == 0) {
      float z = p + bc2[0];
      out[b0 + g] = 1.f / (1.f + expf(-z));
    }
  }
}

extern "C" void kernel_launch(void* const* d_in, const int* in_sizes, int n_in,
                              void* d_out, int out_size, void* d_ws,
                              size_t ws_size, hipStream_t stream) {
  (void)in_sizes; (void)n_in; (void)out_size;
  const float* nf  = (const float*)d_in[0];
  const float* nbf = (const float*)d_in[1];
  const float* ntm = (const float*)d_in[2];
  const float* nbt = (const float*)d_in[3];
  const float* tf  = (const float*)d_in[4];
  const float* tp  = (const float*)d_in[5];
  const float* Wq  = (const float*)d_in[6];
  const float* bq  = (const float*)d_in[7];
  const float* Wk  = (const float*)d_in[8];
  // d_in[9] = bk: n-uniform score shift -> softmax-invariant -> dropped
  const float* Wv  = (const float*)d_in[10];
  const float* bv  = (const float*)d_in[11];
  const float* Wo  = (const float*)d_in[12];
  const float* bo  = (const float*)d_in[13];
  const float* W1  = (const float*)d_in[14];
  const float* b1  = (const float*)d_in[15];
  const float* W2  = (const float*)d_in[16];
  const float* b2  = (const float*)d_in[17];
  const float* g1  = (const float*)d_in[18];
  const float* be1 = (const float*)d_in[19];
  const float* g2  = (const float*)d_in[20];
  const float* be2 = (const float*)d_in[21];
  const float* Wc1 = (const float*)d_in[22];
  const float* bc1 = (const float*)d_in[23];
  const float* Wc2 = (const float*)d_in[24];
  const float* bc2 = (const float*)d_in[25];
  const int* mask  = (const int*)d_in[26];
  float* out = (float*)d_out;

  // Workspace (bytes):
  //   WF   0 .. 622,592
  //   mb   622,592 .. 1,022,592
  //   tqf  1,022,592 .. 26,622,592
  //   rb   26,622,592 .. 180,222,592   (bf16; u aliases)
  //   h1b  180,222,592 .. 231,422,592  (bf16)
  //   xfb  231,422,592 .. 282,622,592  (f32)   <- NEED
  const size_t NEED = 282622592ull;
  if (ws_size >= NEED) {
    char* w = (char*)d_ws;
    unsigned short* WF = (unsigned short*)w;
    unsigned* mb = (unsigned*)(w + 622592);
    float* tqf = (float*)(w + 1022592);
    unsigned short* rb = (unsigned short*)(w + 26622592);
    unsigned short* h1b = (unsigned short*)(w + 180222592);
    float* xfb = (float*)(w + 231422592);

    conv_w<<<608, 256, 0, stream>>>(Wq, Wk, Wv, Wo, W1, W2, WF);
    prep_tq<<<25000, 256, 0, stream>>>(ntm, tf, tp, tqf);
    prep_mb<<<(BB + 255) / 256, 256, 0, stream>>>(mask, mb);

    const float* xsrc = nf;
    for (int l = 0; l < NL; ++l) {
      const unsigned short* WFl = WF + (size_t)l * 155648;
      // y -> r fused (yb round trip eliminated)
      gemm_yr<<<6250, 256, 0, stream>>>(xsrc, tqf, WFl, bq + l * HD, rb);
      // scores/softmax/u (u bf16 overwrites r; kc recomputed in-kernel)
      attn_b<<<50000, 256, 0, stream>>>(nbf, nbt, tf, tp, mb, rb, rb);
      // a -> LN1 -> FF1 fused (ab round trip + xfb re-read eliminated)
      gemm_aln1ff1<<<6250, 256, 0, stream>>>(
          rb, WFl, bv + l * HD, bo + l * ND, xsrc, g1 + l * ND, be1 + l * ND,
          b1 + l * 2 * ND, xfb, h1b);
      // x = LN2(x + h1 @ W2 + b2); final layer: classifier fused in epilogue
      if (l == NL - 1)
        gemm_ln<1, 1><<<6250, 256, 0, stream>>>(
            h1b, 2 * ND, 8, WFl + 122880, b2 + l * ND, xfb, g2 + l * ND,
            be2 + l * ND, xfb, Wc1, bc1, Wc2, bc2, out);
      else
        gemm_ln<1, 0><<<6250, 256, 0, stream>>>(
            h1b, 2 * ND, 8, WFl + 122880, b2 + l * ND, xfb, g2 + l * ND,
            be2 + l * ND, xfb, nullptr, nullptr, nullptr, nullptr, nullptr);
      xsrc = xfb;
    }
  } else {
    tgat_fused<<<BB / G, T, 0, stream>>>(nf, nbf, ntm, nbt, tf, tp, Wq, bq, Wk,
                                         Wv, bv, Wo, bo, W1, b1, W2, b2, g1,
                                         be1, g2, be2, Wc1, bc1, Wc2, bc2,
                                         mask, out);
  }
}